// Round 1
// baseline (2020.338 us; speedup 1.0000x reference)
//
#include <hip/hip_runtime.h>

#define DIM 128
constexpr float EPS = 1e-5f;

// ---------------- degree / dinv ----------------
__global__ void k_count_deg(const int* __restrict__ dst, float* __restrict__ deg, int E) {
    int e = blockIdx.x * blockDim.x + threadIdx.x;
    if (e < E) atomicAdd(&deg[dst[e]], 1.0f);
}

__global__ void k_dinv(float* __restrict__ deg, int n) {
    int i = blockIdx.x * blockDim.x + threadIdx.x;
    if (i < n) deg[i] = rsqrtf(deg[i] + 1.0f);
}

// ---------------- GEMM: out[n,128] = in[n,128] @ W[128,128] ----------------
__global__ __launch_bounds__(256) void k_matmul(const float* __restrict__ in,
                                                const float* __restrict__ W,
                                                float* __restrict__ out, int n) {
    __shared__ float sW[DIM * DIM];  // 64 KB
    for (int i = threadIdx.x; i < DIM * DIM; i += 256) sW[i] = W[i];
    __syncthreads();

    int rg = threadIdx.x >> 5;          // 0..7
    int cg = (threadIdx.x & 31) * 4;    // 0..124
    int row0 = blockIdx.x * 32 + rg * 4;

    float acc[4][4] = {};
    if (row0 + 4 <= n) {
        for (int k = 0; k < DIM; k += 4) {
            float4 w0 = *(const float4*)&sW[(k + 0) * DIM + cg];
            float4 w1 = *(const float4*)&sW[(k + 1) * DIM + cg];
            float4 w2 = *(const float4*)&sW[(k + 2) * DIM + cg];
            float4 w3 = *(const float4*)&sW[(k + 3) * DIM + cg];
#pragma unroll
            for (int i = 0; i < 4; ++i) {
                float4 a = *(const float4*)&in[(size_t)(row0 + i) * DIM + k];
                acc[i][0] += a.x * w0.x + a.y * w1.x + a.z * w2.x + a.w * w3.x;
                acc[i][1] += a.x * w0.y + a.y * w1.y + a.z * w2.y + a.w * w3.y;
                acc[i][2] += a.x * w0.z + a.y * w1.z + a.z * w2.z + a.w * w3.z;
                acc[i][3] += a.x * w0.w + a.y * w1.w + a.z * w2.w + a.w * w3.w;
            }
        }
#pragma unroll
        for (int i = 0; i < 4; ++i) {
            *(float4*)&out[(size_t)(row0 + i) * DIM + cg] =
                make_float4(acc[i][0], acc[i][1], acc[i][2], acc[i][3]);
        }
    } else {
        for (int k = 0; k < DIM; k += 4) {
            float4 w0 = *(const float4*)&sW[(k + 0) * DIM + cg];
            float4 w1 = *(const float4*)&sW[(k + 1) * DIM + cg];
            float4 w2 = *(const float4*)&sW[(k + 2) * DIM + cg];
            float4 w3 = *(const float4*)&sW[(k + 3) * DIM + cg];
            for (int i = 0; i < 4; ++i) {
                int r = row0 + i;
                if (r >= n) break;
                float4 a = *(const float4*)&in[(size_t)r * DIM + k];
                acc[i][0] += a.x * w0.x + a.y * w1.x + a.z * w2.x + a.w * w3.x;
                acc[i][1] += a.x * w0.y + a.y * w1.y + a.z * w2.y + a.w * w3.y;
                acc[i][2] += a.x * w0.z + a.y * w1.z + a.z * w2.z + a.w * w3.z;
                acc[i][3] += a.x * w0.w + a.y * w1.w + a.z * w2.w + a.w * w3.w;
            }
        }
        for (int i = 0; i < 4; ++i) {
            int r = row0 + i;
            if (r >= n) break;
            *(float4*)&out[(size_t)r * DIM + cg] =
                make_float4(acc[i][0], acc[i][1], acc[i][2], acc[i][3]);
        }
    }
}

// ---------------- agg init: agg = h * dinv^2 + b ----------------
__global__ void k_init_agg(const float* __restrict__ h, const float* __restrict__ dinv,
                           const float* __restrict__ b, float* __restrict__ agg, int n) {
    int idx = blockIdx.x * blockDim.x + threadIdx.x;
    if (idx >= n * DIM) return;
    int i = idx >> 7, c = idx & 127;
    float dv = dinv[i];
    agg[idx] = h[idx] * dv * dv + b[c];
}

// ---------------- edge scatter: agg[dst] += h[src]*dinv[src]*dinv[dst] ----------------
__global__ __launch_bounds__(256) void k_scatter(const float* __restrict__ h,
                                                 const int* __restrict__ src,
                                                 const int* __restrict__ dst,
                                                 const float* __restrict__ dinv,
                                                 float* __restrict__ agg, int E) {
    int wave = (blockIdx.x * 256 + threadIdx.x) >> 6;
    int lane = threadIdx.x & 63;
    if (wave >= E) return;
    int s = src[wave], d = dst[wave];
    float sc = dinv[s] * dinv[d];
    const float2 hv = *(const float2*)&h[(size_t)s * DIM + lane * 2];
    atomicAdd(&agg[(size_t)d * DIM + lane * 2 + 0], hv.x * sc);
    atomicAdd(&agg[(size_t)d * DIM + lane * 2 + 1], hv.y * sc);
}

// ---------------- BN stats: per-channel sum / sumsq ----------------
__global__ __launch_bounds__(128) void k_stats(const float* __restrict__ x,
                                               float* __restrict__ stats, int n) {
    int c = threadIdx.x;
    int r0 = blockIdx.x * 128;
    int r1 = min(n, r0 + 128);
    float s = 0.f, s2 = 0.f;
    for (int r = r0; r < r1; ++r) {
        float v = x[(size_t)r * DIM + c];
        s += v;
        s2 += v * v;
    }
    atomicAdd(&stats[c], s);
    atomicAdd(&stats[DIM + c], s2);
}

// ---------------- BN apply (+optional relu), in-place ----------------
__global__ void k_bn(float* __restrict__ x, const float* __restrict__ stats,
                     const float* __restrict__ g, const float* __restrict__ be,
                     int n, float inv_n, int relu) {
    int idx = blockIdx.x * blockDim.x + threadIdx.x;
    if (idx >= n * DIM) return;
    int c = idx & 127;
    float mu = stats[c] * inv_n;
    float var = stats[DIM + c] * inv_n - mu * mu;
    float v = (x[idx] - mu) * rsqrtf(var + EPS) * g[c] + be[c];
    if (relu) v = fmaxf(v, 0.f);
    x[idx] = v;
}

// ---------------- pool: out[seg] += h[i]; cnt[seg] += 1 ----------------
__global__ void k_pool(const float* __restrict__ h, const int* __restrict__ batch,
                       float* __restrict__ out, float* __restrict__ cnt, int n) {
    int idx = blockIdx.x * blockDim.x + threadIdx.x;
    if (idx >= n * DIM) return;
    int i = idx >> 7, c = idx & 127;
    int seg = batch[i] - batch[0];
    atomicAdd(&out[(size_t)seg * DIM + c], h[idx]);
    if (c == 0) atomicAdd(&cnt[seg], 1.0f);
}

__global__ void k_div(float* __restrict__ out, const float* __restrict__ cnt, int total) {
    int idx = blockIdx.x * blockDim.x + threadIdx.x;
    if (idx >= total) return;
    out[idx] /= fmaxf(cnt[idx >> 7], 1.0f);
}

// ---------------- launch ----------------
extern "C" void kernel_launch(void* const* d_in, const int* in_sizes, int n_in,
                              void* d_out, int out_size, void* d_ws, size_t ws_size,
                              hipStream_t stream) {
    const float* x = (const float*)d_in[0];
    const int* edge_index = (const int*)d_in[1];
    const int* batch = (const int*)d_in[3];
    const float* W1 = (const float*)d_in[4];
    const float* b1 = (const float*)d_in[5];
    const float* g1 = (const float*)d_in[6];
    const float* be1 = (const float*)d_in[7];
    const float* Wm = (const float*)d_in[8];
    const float* bm = (const float*)d_in[9];
    const float* gm = (const float*)d_in[10];
    const float* bem = (const float*)d_in[11];
    const float* W2 = (const float*)d_in[12];
    const float* b2 = (const float*)d_in[13];
    const float* g2 = (const float*)d_in[14];
    const float* be2 = (const float*)d_in[15];

    int n = in_sizes[0] / DIM;
    int E = in_sizes[1] / 2;
    int G = out_size / DIM;

    const int* srcI = edge_index;
    const int* dstI = edge_index + E;

    float* dinv = (float*)d_ws;
    float* bufA = dinv + n;                       // h = in @ W
    float* bufB = bufA + (size_t)n * DIM;         // agg / layer output
    float* stats = bufB + (size_t)n * DIM;        // 2*DIM
    float* cnt = stats + 2 * DIM;                 // G

    float* out = (float*)d_out;

    // degree -> dinv
    hipMemsetAsync(dinv, 0, (size_t)n * sizeof(float), stream);
    k_count_deg<<<(E + 255) / 256, 256, 0, stream>>>(dstI, dinv, E);
    k_dinv<<<(n + 255) / 256, 256, 0, stream>>>(dinv, n);

    struct Layer { const float *W, *b, *g, *be; int relu; };
    Layer L[3] = {
        {W1, b1, g1, be1, 1},
        {Wm, bm, gm, bem, 1},
        {W2, b2, g2, be2, 0},
    };

    const float* in = x;
    int elemBlocks = (n * DIM + 255) / 256;
    for (int l = 0; l < 3; ++l) {
        k_matmul<<<(n + 31) / 32, 256, 0, stream>>>(in, L[l].W, bufA, n);
        k_init_agg<<<elemBlocks, 256, 0, stream>>>(bufA, dinv, L[l].b, bufB, n);
        k_scatter<<<(E + 3) / 4, 256, 0, stream>>>(bufA, srcI, dstI, dinv, bufB, E);
        hipMemsetAsync(stats, 0, 2 * DIM * sizeof(float), stream);
        k_stats<<<(n + 127) / 128, 128, 0, stream>>>(bufB, stats, n);
        k_bn<<<elemBlocks, 256, 0, stream>>>(bufB, stats, L[l].g, L[l].be, n,
                                             1.0f / (float)n, L[l].relu);
        in = bufB;
    }

    // global mean pool
    hipMemsetAsync(out, 0, (size_t)G * DIM * sizeof(float), stream);
    hipMemsetAsync(cnt, 0, (size_t)G * sizeof(float), stream);
    k_pool<<<elemBlocks, 256, 0, stream>>>(bufB, batch, out, cnt, n);
    k_div<<<(G * DIM + 255) / 256, 256, 0, stream>>>(out, cnt, G * DIM);
}

// Round 2
// 967.777 us; speedup vs baseline: 2.0876x; 2.0876x over previous
//
#include <hip/hip_runtime.h>

#define DIM 128
constexpr float EPS = 1e-5f;

// ---------------- degree (int) ----------------
__global__ void k_count_deg(const int* __restrict__ dst, int* __restrict__ degi, int E) {
    int e = blockIdx.x * blockDim.x + threadIdx.x;
    if (e < E) atomicAdd(&degi[dst[e]], 1);
}

__global__ void k_dinv(const int* __restrict__ degi, float* __restrict__ dinv, int n) {
    int i = blockIdx.x * blockDim.x + threadIdx.x;
    if (i < n) dinv[i] = rsqrtf((float)degi[i] + 1.0f);
}

// ---------------- exclusive scan of degi -> row_ptr (single block) ----------------
__global__ __launch_bounds__(1024) void k_scan(const int* __restrict__ degi,
                                               int* __restrict__ row_ptr, int n) {
    __shared__ int ws[16];
    __shared__ int carry;
    if (threadIdx.x == 0) carry = 0;
    __syncthreads();
    int lane = threadIdx.x & 63;
    int wv = threadIdx.x >> 6;  // 0..15
    for (int base = 0; base < n; base += 1024) {
        int i = base + threadIdx.x;
        int v = (i < n) ? degi[i] : 0;
        int sc = v;
#pragma unroll
        for (int off = 1; off < 64; off <<= 1) {
            int t = __shfl_up(sc, off, 64);
            if (lane >= off) sc += t;
        }
        if (lane == 63) ws[wv] = sc;
        __syncthreads();
        if (threadIdx.x < 16) {
            int t = ws[threadIdx.x];
#pragma unroll
            for (int off = 1; off < 16; off <<= 1) {
                int u = __shfl_up(t, off, 64);
                if ((int)threadIdx.x >= off) t += u;
            }
            ws[threadIdx.x] = t;  // inclusive over wave sums
        }
        __syncthreads();
        int waveoff = (wv > 0) ? ws[wv - 1] : 0;
        if (i < n) row_ptr[i] = carry + waveoff + sc - v;  // exclusive
        __syncthreads();
        if (threadIdx.x == 0) carry += ws[15];
        __syncthreads();
    }
    if (threadIdx.x == 0) row_ptr[n] = carry;
}

__global__ void k_copy_int(const int* __restrict__ a, int* __restrict__ b, int n) {
    int i = blockIdx.x * blockDim.x + threadIdx.x;
    if (i < n) b[i] = a[i];
}

// ---------------- fill CSR: csr_src grouped by dst ----------------
__global__ void k_fill(const int* __restrict__ src, const int* __restrict__ dst,
                       int* __restrict__ cursor, int* __restrict__ csr_src, int E) {
    int e = blockIdx.x * blockDim.x + threadIdx.x;
    if (e >= E) return;
    int d = dst[e];
    int slot = atomicAdd(&cursor[d], 1);
    csr_src[slot] = src[e];
}

// ---------------- GEMM: out[n,128] = (in[n,128] @ W[128,128]) * dinv[row] ----------------
__global__ __launch_bounds__(256) void k_matmul(const float* __restrict__ in,
                                                const float* __restrict__ W,
                                                const float* __restrict__ dinv,
                                                float* __restrict__ out, int n) {
    __shared__ float sW[DIM * DIM];  // 64 KB
    for (int i = threadIdx.x; i < DIM * DIM; i += 256) sW[i] = W[i];
    __syncthreads();

    int rg = threadIdx.x >> 5;        // 0..7
    int cg = (threadIdx.x & 31) * 4;  // 0..124
    int row0 = blockIdx.x * 32 + rg * 4;

    float acc[4][4] = {};
    int rmax = min(4, n - row0);
    if (rmax <= 0) return;
    for (int k = 0; k < DIM; k += 4) {
        float4 w0 = *(const float4*)&sW[(k + 0) * DIM + cg];
        float4 w1 = *(const float4*)&sW[(k + 1) * DIM + cg];
        float4 w2 = *(const float4*)&sW[(k + 2) * DIM + cg];
        float4 w3 = *(const float4*)&sW[(k + 3) * DIM + cg];
#pragma unroll
        for (int i = 0; i < 4; ++i) {
            if (i >= rmax) break;
            float4 a = *(const float4*)&in[(size_t)(row0 + i) * DIM + k];
            acc[i][0] += a.x * w0.x + a.y * w1.x + a.z * w2.x + a.w * w3.x;
            acc[i][1] += a.x * w0.y + a.y * w1.y + a.z * w2.y + a.w * w3.y;
            acc[i][2] += a.x * w0.z + a.y * w1.z + a.z * w2.z + a.w * w3.z;
            acc[i][3] += a.x * w0.w + a.y * w1.w + a.z * w2.w + a.w * w3.w;
        }
    }
#pragma unroll
    for (int i = 0; i < 4; ++i) {
        if (i >= rmax) break;
        float dv = dinv[row0 + i];
        *(float4*)&out[(size_t)(row0 + i) * DIM + cg] =
            make_float4(acc[i][0] * dv, acc[i][1] * dv, acc[i][2] * dv, acc[i][3] * dv);
    }
}

// ---------------- gather: agg[d] = dinv[d]*(sum_e hs[src] + hs[d]) + b ----------------
__global__ __launch_bounds__(256) void k_gather(const float* __restrict__ hs,
                                                const int* __restrict__ csr_src,
                                                const int* __restrict__ row_ptr,
                                                const float* __restrict__ dinv,
                                                const float* __restrict__ b,
                                                float* __restrict__ agg, int n) {
    int node = (blockIdx.x * 256 + threadIdx.x) >> 6;
    int lane = threadIdx.x & 63;
    if (node >= n) return;
    int beg = row_ptr[node], end = row_ptr[node + 1];
    float2 acc = {0.f, 0.f};
    for (int e = beg; e < end; ++e) {
        int s = csr_src[e];
        float2 hv = *(const float2*)&hs[(size_t)s * DIM + lane * 2];
        acc.x += hv.x;
        acc.y += hv.y;
    }
    float2 hself = *(const float2*)&hs[(size_t)node * DIM + lane * 2];
    float dv = dinv[node];
    float2 o;
    o.x = (acc.x + hself.x) * dv + b[lane * 2 + 0];
    o.y = (acc.y + hself.y) * dv + b[lane * 2 + 1];
    *(float2*)&agg[(size_t)node * DIM + lane * 2] = o;
}

// ---------------- BN stats: per-channel sum / sumsq ----------------
__global__ __launch_bounds__(128) void k_stats(const float* __restrict__ x,
                                               float* __restrict__ stats, int n) {
    int c = threadIdx.x;
    int r0 = blockIdx.x * 128;
    int r1 = min(n, r0 + 128);
    float s = 0.f, s2 = 0.f;
    for (int r = r0; r < r1; ++r) {
        float v = x[(size_t)r * DIM + c];
        s += v;
        s2 += v * v;
    }
    atomicAdd(&stats[c], s);
    atomicAdd(&stats[DIM + c], s2);
}

// ---------------- BN apply (+optional relu), in-place ----------------
__global__ void k_bn(float* __restrict__ x, const float* __restrict__ stats,
                     const float* __restrict__ g, const float* __restrict__ be,
                     int n, float inv_n, int relu) {
    int idx = blockIdx.x * blockDim.x + threadIdx.x;
    if (idx >= n * DIM) return;
    int c = idx & 127;
    float mu = stats[c] * inv_n;
    float var = stats[DIM + c] * inv_n - mu * mu;
    float v = (x[idx] - mu) * rsqrtf(var + EPS) * g[c] + be[c];
    if (relu) v = fmaxf(v, 0.f);
    x[idx] = v;
}

// ---------------- pool ----------------
__global__ void k_pool(const float* __restrict__ h, const int* __restrict__ batch,
                       float* __restrict__ out, float* __restrict__ cnt, int n) {
    int idx = blockIdx.x * blockDim.x + threadIdx.x;
    if (idx >= n * DIM) return;
    int i = idx >> 7, c = idx & 127;
    int seg = batch[i] - batch[0];
    atomicAdd(&out[(size_t)seg * DIM + c], h[idx]);
    if (c == 0) atomicAdd(&cnt[seg], 1.0f);
}

__global__ void k_div(float* __restrict__ out, const float* __restrict__ cnt, int total) {
    int idx = blockIdx.x * blockDim.x + threadIdx.x;
    if (idx >= total) return;
    out[idx] /= fmaxf(cnt[idx >> 7], 1.0f);
}

// ---------------- launch ----------------
extern "C" void kernel_launch(void* const* d_in, const int* in_sizes, int n_in,
                              void* d_out, int out_size, void* d_ws, size_t ws_size,
                              hipStream_t stream) {
    const float* x = (const float*)d_in[0];
    const int* edge_index = (const int*)d_in[1];
    const int* batch = (const int*)d_in[3];
    const float* W1 = (const float*)d_in[4];
    const float* b1 = (const float*)d_in[5];
    const float* g1 = (const float*)d_in[6];
    const float* be1 = (const float*)d_in[7];
    const float* Wm = (const float*)d_in[8];
    const float* bm = (const float*)d_in[9];
    const float* gm = (const float*)d_in[10];
    const float* bem = (const float*)d_in[11];
    const float* W2 = (const float*)d_in[12];
    const float* b2 = (const float*)d_in[13];
    const float* g2 = (const float*)d_in[14];
    const float* be2 = (const float*)d_in[15];

    int n = in_sizes[0] / DIM;
    int E = in_sizes[1] / 2;
    int G = out_size / DIM;

    const int* srcI = edge_index;
    const int* dstI = edge_index + E;

    char* p = (char*)d_ws;
    float* bufA = (float*)p;            p += (size_t)n * DIM * 4;   // hs = (in@W)*dinv
    float* bufB = (float*)p;            p += (size_t)n * DIM * 4;   // agg / layer out
    float* dinv = (float*)p;            p += (size_t)n * 4;
    int* degi = (int*)p;                p += (size_t)n * 4;
    int* row_ptr = (int*)p;             p += (size_t)(n + 1) * 4;
    int* cursor = (int*)p;              p += (size_t)n * 4;
    int* csr_src = (int*)p;             p += (size_t)E * 4;
    float* stats = (float*)p;           p += 2 * DIM * 4;
    float* cnt = (float*)p;             p += (size_t)G * 4;

    float* out = (float*)d_out;

    // ---- CSR build ----
    hipMemsetAsync(degi, 0, (size_t)n * sizeof(int), stream);
    k_count_deg<<<(E + 255) / 256, 256, 0, stream>>>(dstI, degi, E);
    k_dinv<<<(n + 255) / 256, 256, 0, stream>>>(degi, dinv, n);
    k_scan<<<1, 1024, 0, stream>>>(degi, row_ptr, n);
    k_copy_int<<<(n + 255) / 256, 256, 0, stream>>>(row_ptr, cursor, n);
    k_fill<<<(E + 255) / 256, 256, 0, stream>>>(srcI, dstI, cursor, csr_src, E);

    struct Layer { const float *W, *b, *g, *be; int relu; };
    Layer L[3] = {
        {W1, b1, g1, be1, 1},
        {Wm, bm, gm, bem, 1},
        {W2, b2, g2, be2, 0},
    };

    const float* in = x;
    int elemBlocks = (n * DIM + 255) / 256;
    int gatherBlocks = (n + 3) / 4;  // 4 nodes (waves) per 256-thread block
    for (int l = 0; l < 3; ++l) {
        k_matmul<<<(n + 31) / 32, 256, 0, stream>>>(in, L[l].W, dinv, bufA, n);
        k_gather<<<gatherBlocks, 256, 0, stream>>>(bufA, csr_src, row_ptr, dinv,
                                                   L[l].b, bufB, n);
        hipMemsetAsync(stats, 0, 2 * DIM * sizeof(float), stream);
        k_stats<<<(n + 127) / 128, 128, 0, stream>>>(bufB, stats, n);
        k_bn<<<elemBlocks, 256, 0, stream>>>(bufB, stats, L[l].g, L[l].be, n,
                                             1.0f / (float)n, L[l].relu);
        in = bufB;
    }

    // global mean pool
    hipMemsetAsync(out, 0, (size_t)G * DIM * sizeof(float), stream);
    hipMemsetAsync(cnt, 0, (size_t)G * sizeof(float), stream);
    k_pool<<<elemBlocks, 256, 0, stream>>>(bufB, batch, out, cnt, n);
    k_div<<<(G * DIM + 255) / 256, 256, 0, stream>>>(out, cnt, G * DIM);
}

// Round 3
// 833.999 us; speedup vs baseline: 2.4225x; 1.1604x over previous
//
#include <hip/hip_runtime.h>

#define DIM 128
constexpr float EPS = 1e-5f;

// ---------------- degree (int) ----------------
__global__ void k_count_deg(const int* __restrict__ dst, int* __restrict__ degi, int E) {
    int e = blockIdx.x * blockDim.x + threadIdx.x;
    if (e < E) atomicAdd(&degi[dst[e]], 1);
}

__global__ void k_dinv(const int* __restrict__ degi, float* __restrict__ dinv, int n) {
    int i = blockIdx.x * blockDim.x + threadIdx.x;
    if (i < n) dinv[i] = rsqrtf((float)degi[i] + 1.0f);
}

// ---------------- exclusive scan of degi -> row_ptr (single block) ----------------
__global__ __launch_bounds__(1024) void k_scan(const int* __restrict__ degi,
                                               int* __restrict__ row_ptr, int n) {
    __shared__ int ws[16];
    __shared__ int carry;
    if (threadIdx.x == 0) carry = 0;
    __syncthreads();
    int lane = threadIdx.x & 63;
    int wv = threadIdx.x >> 6;  // 0..15
    for (int base = 0; base < n; base += 1024) {
        int i = base + threadIdx.x;
        int v = (i < n) ? degi[i] : 0;
        int sc = v;
#pragma unroll
        for (int off = 1; off < 64; off <<= 1) {
            int t = __shfl_up(sc, off, 64);
            if (lane >= off) sc += t;
        }
        if (lane == 63) ws[wv] = sc;
        __syncthreads();
        if (threadIdx.x < 16) {
            int t = ws[threadIdx.x];
#pragma unroll
            for (int off = 1; off < 16; off <<= 1) {
                int u = __shfl_up(t, off, 64);
                if ((int)threadIdx.x >= off) t += u;
            }
            ws[threadIdx.x] = t;  // inclusive over wave sums
        }
        __syncthreads();
        int waveoff = (wv > 0) ? ws[wv - 1] : 0;
        if (i < n) row_ptr[i] = carry + waveoff + sc - v;  // exclusive
        __syncthreads();
        if (threadIdx.x == 0) carry += ws[15];
        __syncthreads();
    }
    if (threadIdx.x == 0) row_ptr[n] = carry;
}

__global__ void k_copy_int(const int* __restrict__ a, int* __restrict__ b, int n) {
    int i = blockIdx.x * blockDim.x + threadIdx.x;
    if (i < n) b[i] = a[i];
}

// ---------------- fill CSR: csr_src grouped by dst ----------------
__global__ void k_fill(const int* __restrict__ src, const int* __restrict__ dst,
                       int* __restrict__ cursor, int* __restrict__ csr_src, int E) {
    int e = blockIdx.x * blockDim.x + threadIdx.x;
    if (e >= E) return;
    int d = dst[e];
    int slot = atomicAdd(&cursor[d], 1);
    csr_src[slot] = src[e];
}

// ---------------- GEMM: out[n,128] = (in[n,128] @ W[128,128]) * dinv[row] ----------------
__global__ __launch_bounds__(256) void k_matmul(const float* __restrict__ in,
                                                const float* __restrict__ W,
                                                const float* __restrict__ dinv,
                                                float* __restrict__ out, int n) {
    __shared__ float sW[DIM * DIM];  // 64 KB
    for (int i = threadIdx.x; i < DIM * DIM; i += 256) sW[i] = W[i];
    __syncthreads();

    int rg = threadIdx.x >> 5;        // 0..7
    int cg = (threadIdx.x & 31) * 4;  // 0..124
    int row0 = blockIdx.x * 32 + rg * 4;

    float acc[4][4] = {};
    int rmax = min(4, n - row0);
    if (rmax <= 0) return;
    for (int k = 0; k < DIM; k += 4) {
        float4 w0 = *(const float4*)&sW[(k + 0) * DIM + cg];
        float4 w1 = *(const float4*)&sW[(k + 1) * DIM + cg];
        float4 w2 = *(const float4*)&sW[(k + 2) * DIM + cg];
        float4 w3 = *(const float4*)&sW[(k + 3) * DIM + cg];
#pragma unroll
        for (int i = 0; i < 4; ++i) {
            if (i >= rmax) break;
            float4 a = *(const float4*)&in[(size_t)(row0 + i) * DIM + k];
            acc[i][0] += a.x * w0.x + a.y * w1.x + a.z * w2.x + a.w * w3.x;
            acc[i][1] += a.x * w0.y + a.y * w1.y + a.z * w2.y + a.w * w3.y;
            acc[i][2] += a.x * w0.z + a.y * w1.z + a.z * w2.z + a.w * w3.z;
            acc[i][3] += a.x * w0.w + a.y * w1.w + a.z * w2.w + a.w * w3.w;
        }
    }
#pragma unroll
    for (int i = 0; i < 4; ++i) {
        if (i >= rmax) break;
        float dv = dinv[row0 + i];
        *(float4*)&out[(size_t)(row0 + i) * DIM + cg] =
            make_float4(acc[i][0] * dv, acc[i][1] * dv, acc[i][2] * dv, acc[i][3] * dv);
    }
}

// ---------------- gather: agg[d] = dinv[d]*(sum_e hs[src] + hs[d]) + b ----------------
__global__ __launch_bounds__(256) void k_gather(const float* __restrict__ hs,
                                                const int* __restrict__ csr_src,
                                                const int* __restrict__ row_ptr,
                                                const float* __restrict__ dinv,
                                                const float* __restrict__ b,
                                                float* __restrict__ agg, int n) {
    int node = (blockIdx.x * 256 + threadIdx.x) >> 6;
    int lane = threadIdx.x & 63;
    if (node >= n) return;
    int beg = row_ptr[node], end = row_ptr[node + 1];
    float2 acc = {0.f, 0.f};
    for (int e = beg; e < end; ++e) {
        int s = csr_src[e];
        float2 hv = *(const float2*)&hs[(size_t)s * DIM + lane * 2];
        acc.x += hv.x;
        acc.y += hv.y;
    }
    float2 hself = *(const float2*)&hs[(size_t)node * DIM + lane * 2];
    float dv = dinv[node];
    float2 o;
    o.x = (acc.x + hself.x) * dv + b[lane * 2 + 0];
    o.y = (acc.y + hself.y) * dv + b[lane * 2 + 1];
    *(float2*)&agg[(size_t)node * DIM + lane * 2] = o;
}

// ---------------- BN stats: per-channel sum / sumsq ----------------
__global__ __launch_bounds__(128) void k_stats(const float* __restrict__ x,
                                               float* __restrict__ stats, int n) {
    int c = threadIdx.x;
    int r0 = blockIdx.x * 128;
    int r1 = min(n, r0 + 128);
    float s = 0.f, s2 = 0.f;
    for (int r = r0; r < r1; ++r) {
        float v = x[(size_t)r * DIM + c];
        s += v;
        s2 += v * v;
    }
    atomicAdd(&stats[c], s);
    atomicAdd(&stats[DIM + c], s2);
}

// ---------------- BN apply (+relu), in-place ----------------
__global__ void k_bn(float* __restrict__ x, const float* __restrict__ stats,
                     const float* __restrict__ g, const float* __restrict__ be,
                     int n, float inv_n, int relu) {
    int idx = blockIdx.x * blockDim.x + threadIdx.x;
    if (idx >= n * DIM) return;
    int c = idx & 127;
    float mu = stats[c] * inv_n;
    float var = stats[DIM + c] * inv_n - mu * mu;
    float v = (x[idx] - mu) * rsqrtf(var + EPS) * g[c] + be[c];
    if (relu) v = fmaxf(v, 0.f);
    x[idx] = v;
}

// ---------------- pool (+fused final BN): one block per graph, batch sorted ----------------
__global__ __launch_bounds__(128) void k_pool_bn(const float* __restrict__ x,
                                                 const int* __restrict__ batch,
                                                 const float* __restrict__ stats,
                                                 const float* __restrict__ g,
                                                 const float* __restrict__ be,
                                                 float* __restrict__ out,
                                                 int n, float inv_n) {
    int gseg = blockIdx.x;
    int c = threadIdx.x;
    int b0 = batch[0];
    int target = b0 + gseg;
    // lower_bound(batch, target)
    int lo = 0, hi = n;
    while (lo < hi) { int mid = (lo + hi) >> 1; if (batch[mid] < target) lo = mid + 1; else hi = mid; }
    int start = lo;
    // lower_bound(batch, target+1)
    lo = start; hi = n;
    while (lo < hi) { int mid = (lo + hi) >> 1; if (batch[mid] < target + 1) lo = mid + 1; else hi = mid; }
    int end = lo;

    float s = 0.f;
    for (int r = start; r < end; ++r) s += x[(size_t)r * DIM + c];

    float mu = stats[c] * inv_n;
    float var = stats[DIM + c] * inv_n - mu * mu;
    float scale = rsqrtf(var + EPS) * g[c];
    float shift = be[c] - mu * scale;
    float o = 0.f;
    if (end > start) o = (s / (float)(end - start)) * scale + shift;
    out[(size_t)gseg * DIM + c] = o;
}

// ---------------- launch ----------------
extern "C" void kernel_launch(void* const* d_in, const int* in_sizes, int n_in,
                              void* d_out, int out_size, void* d_ws, size_t ws_size,
                              hipStream_t stream) {
    const float* x = (const float*)d_in[0];
    const int* edge_index = (const int*)d_in[1];
    const int* batch = (const int*)d_in[3];
    const float* W1 = (const float*)d_in[4];
    const float* b1 = (const float*)d_in[5];
    const float* g1 = (const float*)d_in[6];
    const float* be1 = (const float*)d_in[7];
    const float* Wm = (const float*)d_in[8];
    const float* bm = (const float*)d_in[9];
    const float* gm = (const float*)d_in[10];
    const float* bem = (const float*)d_in[11];
    const float* W2 = (const float*)d_in[12];
    const float* b2 = (const float*)d_in[13];
    const float* g2 = (const float*)d_in[14];
    const float* be2 = (const float*)d_in[15];

    int n = in_sizes[0] / DIM;
    int E = in_sizes[1] / 2;
    int G = out_size / DIM;

    const int* srcI = edge_index;
    const int* dstI = edge_index + E;

    char* p = (char*)d_ws;
    float* bufA = (float*)p;            p += (size_t)n * DIM * 4;   // hs = (in@W)*dinv
    float* bufB = (float*)p;            p += (size_t)n * DIM * 4;   // agg / layer out
    float* dinv = (float*)p;            p += (size_t)n * 4;
    int* degi = (int*)p;                p += (size_t)n * 4;
    int* row_ptr = (int*)p;             p += (size_t)(n + 1) * 4;
    int* cursor = (int*)p;              p += (size_t)n * 4;
    int* csr_src = (int*)p;             p += (size_t)E * 4;
    float* stats = (float*)p;           p += 2 * DIM * 4;

    float* out = (float*)d_out;

    // ---- CSR build ----
    hipMemsetAsync(degi, 0, (size_t)n * sizeof(int), stream);
    k_count_deg<<<(E + 255) / 256, 256, 0, stream>>>(dstI, degi, E);
    k_dinv<<<(n + 255) / 256, 256, 0, stream>>>(degi, dinv, n);
    k_scan<<<1, 1024, 0, stream>>>(degi, row_ptr, n);
    k_copy_int<<<(n + 255) / 256, 256, 0, stream>>>(row_ptr, cursor, n);
    k_fill<<<(E + 255) / 256, 256, 0, stream>>>(srcI, dstI, cursor, csr_src, E);

    struct Layer { const float *W, *b, *g, *be; };
    Layer L[3] = {
        {W1, b1, g1, be1},
        {Wm, bm, gm, bem},
        {W2, b2, g2, be2},
    };

    const float* in = x;
    int elemBlocks = (n * DIM + 255) / 256;
    int gatherBlocks = (n + 3) / 4;  // 4 nodes (waves) per 256-thread block
    for (int l = 0; l < 3; ++l) {
        k_matmul<<<(n + 31) / 32, 256, 0, stream>>>(in, L[l].W, dinv, bufA, n);
        k_gather<<<gatherBlocks, 256, 0, stream>>>(bufA, csr_src, row_ptr, dinv,
                                                   L[l].b, bufB, n);
        hipMemsetAsync(stats, 0, 2 * DIM * sizeof(float), stream);
        k_stats<<<(n + 127) / 128, 128, 0, stream>>>(bufB, stats, n);
        if (l < 2) {
            k_bn<<<elemBlocks, 256, 0, stream>>>(bufB, stats, L[l].g, L[l].be, n,
                                                 1.0f / (float)n, 1);
        }
        in = bufB;
    }

    // global mean pool + fused layer-3 BN (affine-of-mean)
    k_pool_bn<<<G, 128, 0, stream>>>(bufB, batch, stats, g2, be2, out,
                                     n, 1.0f / (float)n);
}

// Round 4
// 579.826 us; speedup vs baseline: 3.4844x; 1.4384x over previous
//
#include <hip/hip_runtime.h>

#define DIM 128
constexpr float EPS = 1e-5f;

typedef __attribute__((ext_vector_type(8))) __bf16 bf16x8;
typedef __attribute__((ext_vector_type(4))) float f32x4;

// ---------------- degree (int) ----------------
__global__ void k_count_deg(const int* __restrict__ dst, int* __restrict__ degi, int E) {
    int e = blockIdx.x * blockDim.x + threadIdx.x;
    if (e < E) atomicAdd(&degi[dst[e]], 1);
}

__global__ void k_dinv(const int* __restrict__ degi, float* __restrict__ dinv, int n) {
    int i = blockIdx.x * blockDim.x + threadIdx.x;
    if (i < n) dinv[i] = rsqrtf((float)degi[i] + 1.0f);
}

// ---------------- exclusive scan of degi -> row_ptr (single block) ----------------
__global__ __launch_bounds__(1024) void k_scan(const int* __restrict__ degi,
                                               int* __restrict__ row_ptr, int n) {
    __shared__ int ws[16];
    __shared__ int carry;
    if (threadIdx.x == 0) carry = 0;
    __syncthreads();
    int lane = threadIdx.x & 63;
    int wv = threadIdx.x >> 6;  // 0..15
    for (int base = 0; base < n; base += 1024) {
        int i = base + threadIdx.x;
        int v = (i < n) ? degi[i] : 0;
        int sc = v;
#pragma unroll
        for (int off = 1; off < 64; off <<= 1) {
            int t = __shfl_up(sc, off, 64);
            if (lane >= off) sc += t;
        }
        if (lane == 63) ws[wv] = sc;
        __syncthreads();
        if (threadIdx.x < 16) {
            int t = ws[threadIdx.x];
#pragma unroll
            for (int off = 1; off < 16; off <<= 1) {
                int u = __shfl_up(t, off, 64);
                if ((int)threadIdx.x >= off) t += u;
            }
            ws[threadIdx.x] = t;  // inclusive over wave sums
        }
        __syncthreads();
        int waveoff = (wv > 0) ? ws[wv - 1] : 0;
        if (i < n) row_ptr[i] = carry + waveoff + sc - v;  // exclusive
        __syncthreads();
        if (threadIdx.x == 0) carry += ws[15];
        __syncthreads();
    }
    if (threadIdx.x == 0) row_ptr[n] = carry;
}

__global__ void k_copy_int(const int* __restrict__ a, int* __restrict__ b, int n) {
    int i = blockIdx.x * blockDim.x + threadIdx.x;
    if (i < n) b[i] = a[i];
}

// ---------------- fill CSR: csr_src grouped by dst ----------------
__global__ void k_fill(const int* __restrict__ src, const int* __restrict__ dst,
                       int* __restrict__ cursor, int* __restrict__ csr_src, int E) {
    int e = blockIdx.x * blockDim.x + threadIdx.x;
    if (e >= E) return;
    int d = dst[e];
    int slot = atomicAdd(&cursor[d], 1);
    csr_src[slot] = src[e];
}

// ---------------- MFMA GEMM (bf16x3 split precision) ----------------
// out[row,:] = relu_bn_opt(in[row,:]) @ W * dinv[row]
// Per block: 64 rows x 128 cols. 4 waves, wave w owns cols [w*32, w*32+32).
template <bool PRE_BN>
__global__ __launch_bounds__(256) void k_matmul_mfma(
    const float* __restrict__ in, const float* __restrict__ W,
    const float* __restrict__ dinv, const float* __restrict__ stats,
    const float* __restrict__ g, const float* __restrict__ be,
    float inv_n, float* __restrict__ out, int n) {
    __shared__ __align__(16) char sAhi[64 * 256];  // 64 rows x 128 bf16
    __shared__ __align__(16) char sAlo[64 * 256];
    __shared__ float sScale[DIM], sShift[DIM];

    int t = threadIdx.x;
    int w = t >> 6, l = t & 63;
    int row0 = blockIdx.x * 64;

    if (PRE_BN) {
        if (t < DIM) {
            float mu = stats[t] * inv_n;
            float var = stats[DIM + t] * inv_n - mu * mu;
            float sc = rsqrtf(var + EPS) * g[t];
            sScale[t] = sc;
            sShift[t] = be[t] - mu * sc;
        }
        __syncthreads();
    }

    // ---- B (W) fragments in registers: hi/lo bf16 ----
    // frag layout: lane l holds B[k = kt*32 + (l>>4)*8 + j][col]
    bf16x8 bh[2][4], bl[2][4];
    {
        int col = w * 32 + (l & 15);
        int ksub = (l >> 4) * 8;
#pragma unroll
        for (int ct = 0; ct < 2; ++ct) {
            int c2 = col + ct * 16;
#pragma unroll
            for (int kt = 0; kt < 4; ++kt) {
                bf16x8 h8, l8;
#pragma unroll
                for (int j = 0; j < 8; ++j) {
                    float wv = W[(size_t)(kt * 32 + ksub + j) * DIM + c2];
                    __bf16 hv = (__bf16)wv;
                    h8[j] = hv;
                    l8[j] = (__bf16)(wv - (float)hv);
                }
                bh[ct][kt] = h8;
                bl[ct][kt] = l8;
            }
        }
    }

    // ---- stage A tile (64x128) as hi/lo bf16, XOR-swizzled ----
    {
        int r = t >> 2;
        int row_g = row0 + r;
        if (row_g >= n) row_g = n - 1;
        const float* src = in + (size_t)row_g * DIM + (t & 3) * 32;
#pragma unroll
        for (int o = 0; o < 4; ++o) {
            float4 v0 = *(const float4*)(src + o * 8);
            float4 v1 = *(const float4*)(src + o * 8 + 4);
            float vv[8] = {v0.x, v0.y, v0.z, v0.w, v1.x, v1.y, v1.z, v1.w};
            bf16x8 h8, l8;
            int c0 = (t & 3) * 32 + o * 8;
#pragma unroll
            for (int j = 0; j < 8; ++j) {
                float v = vv[j];
                if (PRE_BN) v = fmaxf(v * sScale[c0 + j] + sShift[c0 + j], 0.f);
                __bf16 hv = (__bf16)v;
                h8[j] = hv;
                l8[j] = (__bf16)(v - (float)hv);
            }
            int byte = (r * 256 + (t & 3) * 64 + o * 16) ^ ((r & 7) << 4);
            *(bf16x8*)(sAhi + byte) = h8;
            *(bf16x8*)(sAlo + byte) = l8;
        }
    }
    __syncthreads();

    // ---- MFMA main: 4 row-tiles x 2 col-tiles x 4 k-tiles x 3 products ----
    f32x4 acc[4][2];
#pragma unroll
    for (int rt = 0; rt < 4; ++rt)
#pragma unroll
        for (int ct = 0; ct < 2; ++ct) acc[rt][ct] = (f32x4){0.f, 0.f, 0.f, 0.f};

#pragma unroll
    for (int rt = 0; rt < 4; ++rt) {
        int row_l = rt * 16 + (l & 15);
        int kb = (l >> 4) * 16;  // byte offset of lane's k-subslice in a 64B k-tile
        bf16x8 ah[4], al[4];
#pragma unroll
        for (int kt = 0; kt < 4; ++kt) {
            int byte = (row_l * 256 + kt * 64 + kb) ^ ((row_l & 7) << 4);
            ah[kt] = *(const bf16x8*)(sAhi + byte);
            al[kt] = *(const bf16x8*)(sAlo + byte);
        }
#pragma unroll
        for (int ct = 0; ct < 2; ++ct) {
            f32x4 c = acc[rt][ct];
#pragma unroll
            for (int kt = 0; kt < 4; ++kt) {
                c = __builtin_amdgcn_mfma_f32_16x16x32_bf16(ah[kt], bh[ct][kt], c, 0, 0, 0);
                c = __builtin_amdgcn_mfma_f32_16x16x32_bf16(ah[kt], bl[ct][kt], c, 0, 0, 0);
                c = __builtin_amdgcn_mfma_f32_16x16x32_bf16(al[kt], bh[ct][kt], c, 0, 0, 0);
            }
            acc[rt][ct] = c;
        }
    }

    // ---- epilogue: scale by dinv[row], store ----
    // C/D layout: col = lane&15, row = (lane>>4)*4 + reg
    int colw = w * 32 + (l & 15);
#pragma unroll
    for (int rt = 0; rt < 4; ++rt) {
        int row_l = rt * 16 + ((l >> 4) << 2);
#pragma unroll
        for (int reg = 0; reg < 4; ++reg) {
            int gr = row0 + row_l + reg;
            if (gr >= n) continue;
            float dv = dinv[gr];
#pragma unroll
            for (int ct = 0; ct < 2; ++ct)
                out[(size_t)gr * DIM + colw + ct * 16] = acc[rt][ct][reg] * dv;
        }
    }
}

// ---------------- gather: agg[d] = dinv[d]*(sum_e hs[src] + hs[d]) + b ----------------
__global__ __launch_bounds__(256) void k_gather(const float* __restrict__ hs,
                                                const int* __restrict__ csr_src,
                                                const int* __restrict__ row_ptr,
                                                const float* __restrict__ dinv,
                                                const float* __restrict__ b,
                                                float* __restrict__ agg, int n) {
    int node = (blockIdx.x * 256 + threadIdx.x) >> 6;
    int lane = threadIdx.x & 63;
    if (node >= n) return;
    int beg = row_ptr[node], end = row_ptr[node + 1];
    float2 acc = {0.f, 0.f};
    for (int e = beg; e < end; ++e) {
        int s = csr_src[e];
        float2 hv = *(const float2*)&hs[(size_t)s * DIM + lane * 2];
        acc.x += hv.x;
        acc.y += hv.y;
    }
    float2 hself = *(const float2*)&hs[(size_t)node * DIM + lane * 2];
    float dv = dinv[node];
    float2 o;
    o.x = (acc.x + hself.x) * dv + b[lane * 2 + 0];
    o.y = (acc.y + hself.y) * dv + b[lane * 2 + 1];
    *(float2*)&agg[(size_t)node * DIM + lane * 2] = o;
}

// ---------------- BN stats: per-channel sum / sumsq ----------------
__global__ __launch_bounds__(128) void k_stats(const float* __restrict__ x,
                                               float* __restrict__ stats, int n) {
    int c = threadIdx.x;
    int r0 = blockIdx.x * 128;
    int r1 = min(n, r0 + 128);
    float s = 0.f, s2 = 0.f;
    for (int r = r0; r < r1; ++r) {
        float v = x[(size_t)r * DIM + c];
        s += v;
        s2 += v * v;
    }
    atomicAdd(&stats[c], s);
    atomicAdd(&stats[DIM + c], s2);
}

// ---------------- pool (+fused final BN): one block per graph, batch sorted ----------------
__global__ __launch_bounds__(128) void k_pool_bn(const float* __restrict__ x,
                                                 const int* __restrict__ batch,
                                                 const float* __restrict__ stats,
                                                 const float* __restrict__ g,
                                                 const float* __restrict__ be,
                                                 float* __restrict__ out,
                                                 int n, float inv_n) {
    int gseg = blockIdx.x;
    int c = threadIdx.x;
    int b0 = batch[0];
    int target = b0 + gseg;
    int lo = 0, hi = n;
    while (lo < hi) { int mid = (lo + hi) >> 1; if (batch[mid] < target) lo = mid + 1; else hi = mid; }
    int start = lo;
    lo = start; hi = n;
    while (lo < hi) { int mid = (lo + hi) >> 1; if (batch[mid] < target + 1) lo = mid + 1; else hi = mid; }
    int end = lo;

    float s = 0.f;
    for (int r = start; r < end; ++r) s += x[(size_t)r * DIM + c];

    float mu = stats[c] * inv_n;
    float var = stats[DIM + c] * inv_n - mu * mu;
    float scale = rsqrtf(var + EPS) * g[c];
    float shift = be[c] - mu * scale;
    float o = 0.f;
    if (end > start) o = (s / (float)(end - start)) * scale + shift;
    out[(size_t)gseg * DIM + c] = o;
}

// ---------------- launch ----------------
extern "C" void kernel_launch(void* const* d_in, const int* in_sizes, int n_in,
                              void* d_out, int out_size, void* d_ws, size_t ws_size,
                              hipStream_t stream) {
    const float* x = (const float*)d_in[0];
    const int* edge_index = (const int*)d_in[1];
    const int* batch = (const int*)d_in[3];
    const float* W1 = (const float*)d_in[4];
    const float* b1 = (const float*)d_in[5];
    const float* g1 = (const float*)d_in[6];
    const float* be1 = (const float*)d_in[7];
    const float* Wm = (const float*)d_in[8];
    const float* bm = (const float*)d_in[9];
    const float* gm = (const float*)d_in[10];
    const float* bem = (const float*)d_in[11];
    const float* W2 = (const float*)d_in[12];
    const float* b2 = (const float*)d_in[13];
    const float* g2 = (const float*)d_in[14];
    const float* be2 = (const float*)d_in[15];

    int n = in_sizes[0] / DIM;
    int E = in_sizes[1] / 2;
    int G = out_size / DIM;

    const int* srcI = edge_index;
    const int* dstI = edge_index + E;

    char* p = (char*)d_ws;
    float* bufA = (float*)p;            p += (size_t)n * DIM * 4;   // hs = (in@W)*dinv
    float* bufB = (float*)p;            p += (size_t)n * DIM * 4;   // agg / layer out
    float* dinv = (float*)p;            p += (size_t)n * 4;
    int* degi = (int*)p;                p += (size_t)n * 4;
    int* row_ptr = (int*)p;             p += (size_t)(n + 1) * 4;
    int* cursor = (int*)p;              p += (size_t)n * 4;
    int* csr_src = (int*)p;             p += (size_t)E * 4;
    float* stats = (float*)p;           p += 2 * DIM * 4;

    float* out = (float*)d_out;
    float inv_n = 1.0f / (float)n;

    // ---- CSR build ----
    hipMemsetAsync(degi, 0, (size_t)n * sizeof(int), stream);
    k_count_deg<<<(E + 255) / 256, 256, 0, stream>>>(dstI, degi, E);
    k_dinv<<<(n + 255) / 256, 256, 0, stream>>>(degi, dinv, n);
    k_scan<<<1, 1024, 0, stream>>>(degi, row_ptr, n);
    k_copy_int<<<(n + 255) / 256, 256, 0, stream>>>(row_ptr, cursor, n);
    k_fill<<<(E + 255) / 256, 256, 0, stream>>>(srcI, dstI, cursor, csr_src, E);

    struct Layer { const float *W, *b, *g, *be; };
    Layer L[3] = {
        {W1, b1, g1, be1},
        {Wm, bm, gm, bem},
        {W2, b2, g2, be2},
    };

    const float* in = x;
    int mmBlocks = (n + 63) / 64;
    int gatherBlocks = (n + 3) / 4;  // 4 nodes (waves) per 256-thread block
    for (int l = 0; l < 3; ++l) {
        // BN(l-1)+ReLU fused into A-load for l>=1; dinv-scale fused into epilogue
        if (l == 0)
            k_matmul_mfma<false><<<mmBlocks, 256, 0, stream>>>(
                in, L[l].W, dinv, stats, nullptr, nullptr, inv_n, bufA, n);
        else
            k_matmul_mfma<true><<<mmBlocks, 256, 0, stream>>>(
                in, L[l].W, dinv, stats, L[l - 1].g, L[l - 1].be, inv_n, bufA, n);
        k_gather<<<gatherBlocks, 256, 0, stream>>>(bufA, csr_src, row_ptr, dinv,
                                                   L[l].b, bufB, n);
        hipMemsetAsync(stats, 0, 2 * DIM * sizeof(float), stream);
        k_stats<<<(n + 127) / 128, 128, 0, stream>>>(bufB, stats, n);
        in = bufB;
    }

    // global mean pool + fused layer-3 BN (affine-of-mean)
    k_pool_bn<<<G, 128, 0, stream>>>(bufB, batch, stats, g2, be2, out, n, inv_n);
}

// Round 5
// 508.203 us; speedup vs baseline: 3.9755x; 1.1409x over previous
//
#include <hip/hip_runtime.h>

#define DIM 128
constexpr float EPS = 1e-5f;

typedef __attribute__((ext_vector_type(8))) __bf16 bf16x8;
typedef __attribute__((ext_vector_type(4))) float f32x4;

// ---------------- degree (int) ----------------
__global__ void k_count_deg(const int* __restrict__ dst, int* __restrict__ degi, int E) {
    int e = blockIdx.x * blockDim.x + threadIdx.x;
    if (e < E) atomicAdd(&degi[dst[e]], 1);
}

__global__ void k_dinv(const int* __restrict__ degi, float* __restrict__ dinv, int n) {
    int i = blockIdx.x * blockDim.x + threadIdx.x;
    if (i < n) dinv[i] = rsqrtf((float)degi[i] + 1.0f);
}

// ---------------- exclusive scan of degi -> row_ptr (single block) ----------------
__global__ __launch_bounds__(1024) void k_scan(const int* __restrict__ degi,
                                               int* __restrict__ row_ptr, int n) {
    __shared__ int ws[16];
    __shared__ int carry;
    if (threadIdx.x == 0) carry = 0;
    __syncthreads();
    int lane = threadIdx.x & 63;
    int wv = threadIdx.x >> 6;  // 0..15
    for (int base = 0; base < n; base += 1024) {
        int i = base + threadIdx.x;
        int v = (i < n) ? degi[i] : 0;
        int sc = v;
#pragma unroll
        for (int off = 1; off < 64; off <<= 1) {
            int t = __shfl_up(sc, off, 64);
            if (lane >= off) sc += t;
        }
        if (lane == 63) ws[wv] = sc;
        __syncthreads();
        if (threadIdx.x < 16) {
            int t = ws[threadIdx.x];
#pragma unroll
            for (int off = 1; off < 16; off <<= 1) {
                int u = __shfl_up(t, off, 64);
                if ((int)threadIdx.x >= off) t += u;
            }
            ws[threadIdx.x] = t;  // inclusive over wave sums
        }
        __syncthreads();
        int waveoff = (wv > 0) ? ws[wv - 1] : 0;
        if (i < n) row_ptr[i] = carry + waveoff + sc - v;  // exclusive
        __syncthreads();
        if (threadIdx.x == 0) carry += ws[15];
        __syncthreads();
    }
    if (threadIdx.x == 0) row_ptr[n] = carry;
}

__global__ void k_copy_int(const int* __restrict__ a, int* __restrict__ b, int n) {
    int i = blockIdx.x * blockDim.x + threadIdx.x;
    if (i < n) b[i] = a[i];
}

// ---------------- fill CSR: csr_src grouped by dst ----------------
__global__ void k_fill(const int* __restrict__ src, const int* __restrict__ dst,
                       int* __restrict__ cursor, int* __restrict__ csr_src, int E) {
    int e = blockIdx.x * blockDim.x + threadIdx.x;
    if (e >= E) return;
    int d = dst[e];
    int slot = atomicAdd(&cursor[d], 1);
    csr_src[slot] = src[e];
}

// ---------------- MFMA GEMM (bf16x3 split precision) ----------------
template <bool PRE_BN>
__global__ __launch_bounds__(256) void k_matmul_mfma(
    const float* __restrict__ in, const float* __restrict__ W,
    const float* __restrict__ dinv, const float* __restrict__ stats,
    const float* __restrict__ g, const float* __restrict__ be,
    float inv_n, float* __restrict__ out, int n) {
    __shared__ __align__(16) char sAhi[64 * 256];  // 64 rows x 128 bf16
    __shared__ __align__(16) char sAlo[64 * 256];
    __shared__ float sScale[DIM], sShift[DIM];

    int t = threadIdx.x;
    int w = t >> 6, l = t & 63;
    int row0 = blockIdx.x * 64;

    if (PRE_BN) {
        if (t < DIM) {
            float mu = stats[t] * inv_n;
            float var = stats[DIM + t] * inv_n - mu * mu;
            float sc = rsqrtf(var + EPS) * g[t];
            sScale[t] = sc;
            sShift[t] = be[t] - mu * sc;
        }
        __syncthreads();
    }

    // ---- B (W) fragments in registers: hi/lo bf16 ----
    bf16x8 bh[2][4], bl[2][4];
    {
        int col = w * 32 + (l & 15);
        int ksub = (l >> 4) * 8;
#pragma unroll
        for (int ct = 0; ct < 2; ++ct) {
            int c2 = col + ct * 16;
#pragma unroll
            for (int kt = 0; kt < 4; ++kt) {
                bf16x8 h8, l8;
#pragma unroll
                for (int j = 0; j < 8; ++j) {
                    float wv = W[(size_t)(kt * 32 + ksub + j) * DIM + c2];
                    __bf16 hv = (__bf16)wv;
                    h8[j] = hv;
                    l8[j] = (__bf16)(wv - (float)hv);
                }
                bh[ct][kt] = h8;
                bl[ct][kt] = l8;
            }
        }
    }

    // ---- stage A tile (64x128) as hi/lo bf16, XOR-swizzled ----
    {
        int r = t >> 2;
        int row_g = row0 + r;
        if (row_g >= n) row_g = n - 1;
        const float* src = in + (size_t)row_g * DIM + (t & 3) * 32;
#pragma unroll
        for (int o = 0; o < 4; ++o) {
            float4 v0 = *(const float4*)(src + o * 8);
            float4 v1 = *(const float4*)(src + o * 8 + 4);
            float vv[8] = {v0.x, v0.y, v0.z, v0.w, v1.x, v1.y, v1.z, v1.w};
            bf16x8 h8, l8;
            int c0 = (t & 3) * 32 + o * 8;
#pragma unroll
            for (int j = 0; j < 8; ++j) {
                float v = vv[j];
                if (PRE_BN) v = fmaxf(v * sScale[c0 + j] + sShift[c0 + j], 0.f);
                __bf16 hv = (__bf16)v;
                h8[j] = hv;
                l8[j] = (__bf16)(v - (float)hv);
            }
            int byte = (r * 256 + (t & 3) * 64 + o * 16) ^ ((r & 7) << 4);
            *(bf16x8*)(sAhi + byte) = h8;
            *(bf16x8*)(sAlo + byte) = l8;
        }
    }
    __syncthreads();

    // ---- MFMA main ----
    f32x4 acc[4][2];
#pragma unroll
    for (int rt = 0; rt < 4; ++rt)
#pragma unroll
        for (int ct = 0; ct < 2; ++ct) acc[rt][ct] = (f32x4){0.f, 0.f, 0.f, 0.f};

#pragma unroll
    for (int rt = 0; rt < 4; ++rt) {
        int row_l = rt * 16 + (l & 15);
        int kb = (l >> 4) * 16;
        bf16x8 ah[4], al[4];
#pragma unroll
        for (int kt = 0; kt < 4; ++kt) {
            int byte = (row_l * 256 + kt * 64 + kb) ^ ((row_l & 7) << 4);
            ah[kt] = *(const bf16x8*)(sAhi + byte);
            al[kt] = *(const bf16x8*)(sAlo + byte);
        }
#pragma unroll
        for (int ct = 0; ct < 2; ++ct) {
            f32x4 c = acc[rt][ct];
#pragma unroll
            for (int kt = 0; kt < 4; ++kt) {
                c = __builtin_amdgcn_mfma_f32_16x16x32_bf16(ah[kt], bh[ct][kt], c, 0, 0, 0);
                c = __builtin_amdgcn_mfma_f32_16x16x32_bf16(ah[kt], bl[ct][kt], c, 0, 0, 0);
                c = __builtin_amdgcn_mfma_f32_16x16x32_bf16(al[kt], bh[ct][kt], c, 0, 0, 0);
            }
            acc[rt][ct] = c;
        }
    }

    // ---- epilogue: scale by dinv[row], store ----
    int colw = w * 32 + (l & 15);
#pragma unroll
    for (int rt = 0; rt < 4; ++rt) {
        int row_l = rt * 16 + ((l >> 4) << 2);
#pragma unroll
        for (int reg = 0; reg < 4; ++reg) {
            int gr = row0 + row_l + reg;
            if (gr >= n) continue;
            float dv = dinv[gr];
#pragma unroll
            for (int ct = 0; ct < 2; ++ct)
                out[(size_t)gr * DIM + colw + ct * 16] = acc[rt][ct][reg] * dv;
        }
    }
}

// ---------------- gather: agg[d] = dinv[d]*(sum_e hs[src] + hs[d]) + b ----------------
// One wave per node; 4 edge-parallel groups of 16 lanes; 32 B (8 ch) per lane.
__global__ __launch_bounds__(256) void k_gather(const float* __restrict__ hs,
                                                const int* __restrict__ csr_src,
                                                const int* __restrict__ row_ptr,
                                                const float* __restrict__ dinv,
                                                const float* __restrict__ b,
                                                float* __restrict__ agg, int n) {
    int node = (blockIdx.x * 256 + threadIdx.x) >> 6;
    if (node >= n) return;
    int l = threadIdx.x & 63;
    int grp = l >> 4;      // 0..3: edge-parallel group
    int c8 = (l & 15) * 8; // 8 channels per lane

    f32x4 acc0 = {0.f, 0.f, 0.f, 0.f}, acc1 = {0.f, 0.f, 0.f, 0.f};
    int beg = row_ptr[node], end = row_ptr[node + 1];

    int e = beg + grp;
    // unrolled: 2 edges per group in flight (8 per wave)
    for (; e + 4 < end; e += 8) {
        int s0 = csr_src[e];
        int s1 = csr_src[e + 4];
        const float* p0 = hs + (size_t)s0 * DIM + c8;
        const float* p1 = hs + (size_t)s1 * DIM + c8;
        f32x4 a0 = *(const f32x4*)p0;
        f32x4 a1 = *(const f32x4*)(p0 + 4);
        f32x4 b0 = *(const f32x4*)p1;
        f32x4 b1 = *(const f32x4*)(p1 + 4);
        acc0 += a0; acc1 += a1;
        acc0 += b0; acc1 += b1;
    }
    for (; e < end; e += 4) {
        int s0 = csr_src[e];
        const float* p0 = hs + (size_t)s0 * DIM + c8;
        acc0 += *(const f32x4*)p0;
        acc1 += *(const f32x4*)(p0 + 4);
    }

    // reduce the 4 groups
#pragma unroll
    for (int j = 0; j < 4; ++j) {
        acc0[j] += __shfl_xor(acc0[j], 16, 64);
        acc0[j] += __shfl_xor(acc0[j], 32, 64);
        acc1[j] += __shfl_xor(acc1[j], 16, 64);
        acc1[j] += __shfl_xor(acc1[j], 32, 64);
    }

    if (grp == 0) {
        const float* ps = hs + (size_t)node * DIM + c8;
        f32x4 h0 = *(const f32x4*)ps;
        f32x4 h1 = *(const f32x4*)(ps + 4);
        float dv = dinv[node];
        f32x4 bb0 = *(const f32x4*)(b + c8);
        f32x4 bb1 = *(const f32x4*)(b + c8 + 4);
        f32x4 o0 = (acc0 + h0) * dv + bb0;
        f32x4 o1 = (acc1 + h1) * dv + bb1;
        *(f32x4*)(agg + (size_t)node * DIM + c8) = o0;
        *(f32x4*)(agg + (size_t)node * DIM + c8 + 4) = o1;
    }
}

// ---------------- BN stats: per-channel sum / sumsq ----------------
__global__ __launch_bounds__(128) void k_stats(const float* __restrict__ x,
                                               float* __restrict__ stats, int n) {
    int c = threadIdx.x;
    int r0 = blockIdx.x * 128;
    int r1 = min(n, r0 + 128);
    float s = 0.f, s2 = 0.f;
    for (int r = r0; r < r1; ++r) {
        float v = x[(size_t)r * DIM + c];
        s += v;
        s2 += v * v;
    }
    atomicAdd(&stats[c], s);
    atomicAdd(&stats[DIM + c], s2);
}

// ---------------- pool (+fused final BN): one block per graph, batch sorted ----------------
__global__ __launch_bounds__(128) void k_pool_bn(const float* __restrict__ x,
                                                 const int* __restrict__ batch,
                                                 const float* __restrict__ stats,
                                                 const float* __restrict__ g,
                                                 const float* __restrict__ be,
                                                 float* __restrict__ out,
                                                 int n, float inv_n) {
    int gseg = blockIdx.x;
    int c = threadIdx.x;
    int b0 = batch[0];
    int target = b0 + gseg;
    int lo = 0, hi = n;
    while (lo < hi) { int mid = (lo + hi) >> 1; if (batch[mid] < target) lo = mid + 1; else hi = mid; }
    int start = lo;
    lo = start; hi = n;
    while (lo < hi) { int mid = (lo + hi) >> 1; if (batch[mid] < target + 1) lo = mid + 1; else hi = mid; }
    int end = lo;

    float s = 0.f;
    for (int r = start; r < end; ++r) s += x[(size_t)r * DIM + c];

    float mu = stats[c] * inv_n;
    float var = stats[DIM + c] * inv_n - mu * mu;
    float scale = rsqrtf(var + EPS) * g[c];
    float shift = be[c] - mu * scale;
    float o = 0.f;
    if (end > start) o = (s / (float)(end - start)) * scale + shift;
    out[(size_t)gseg * DIM + c] = o;
}

// ---------------- launch ----------------
extern "C" void kernel_launch(void* const* d_in, const int* in_sizes, int n_in,
                              void* d_out, int out_size, void* d_ws, size_t ws_size,
                              hipStream_t stream) {
    const float* x = (const float*)d_in[0];
    const int* edge_index = (const int*)d_in[1];
    const int* batch = (const int*)d_in[3];
    const float* W1 = (const float*)d_in[4];
    const float* b1 = (const float*)d_in[5];
    const float* g1 = (const float*)d_in[6];
    const float* be1 = (const float*)d_in[7];
    const float* Wm = (const float*)d_in[8];
    const float* bm = (const float*)d_in[9];
    const float* gm = (const float*)d_in[10];
    const float* bem = (const float*)d_in[11];
    const float* W2 = (const float*)d_in[12];
    const float* b2 = (const float*)d_in[13];
    const float* g2 = (const float*)d_in[14];
    const float* be2 = (const float*)d_in[15];

    int n = in_sizes[0] / DIM;
    int E = in_sizes[1] / 2;
    int G = out_size / DIM;

    const int* srcI = edge_index;
    const int* dstI = edge_index + E;

    char* p = (char*)d_ws;
    float* bufA = (float*)p;            p += (size_t)n * DIM * 4;   // hs = (in@W)*dinv
    float* bufB = (float*)p;            p += (size_t)n * DIM * 4;   // agg / layer out
    float* dinv = (float*)p;            p += (size_t)n * 4;
    int* degi = (int*)p;                p += (size_t)n * 4;
    int* row_ptr = (int*)p;             p += (size_t)(n + 1) * 4;
    int* cursor = (int*)p;              p += (size_t)n * 4;
    int* csr_src = (int*)p;             p += (size_t)E * 4;
    float* stats = (float*)p;           p += 2 * DIM * 4;

    float* out = (float*)d_out;
    float inv_n = 1.0f / (float)n;

    // ---- CSR build ----
    hipMemsetAsync(degi, 0, (size_t)n * sizeof(int), stream);
    k_count_deg<<<(E + 255) / 256, 256, 0, stream>>>(dstI, degi, E);
    k_dinv<<<(n + 255) / 256, 256, 0, stream>>>(degi, dinv, n);
    k_scan<<<1, 1024, 0, stream>>>(degi, row_ptr, n);
    k_copy_int<<<(n + 255) / 256, 256, 0, stream>>>(row_ptr, cursor, n);
    k_fill<<<(E + 255) / 256, 256, 0, stream>>>(srcI, dstI, cursor, csr_src, E);

    struct Layer { const float *W, *b, *g, *be; };
    Layer L[3] = {
        {W1, b1, g1, be1},
        {Wm, bm, gm, bem},
        {W2, b2, g2, be2},
    };

    const float* in = x;
    int mmBlocks = (n + 63) / 64;
    int gatherBlocks = (n + 3) / 4;  // 4 nodes (waves) per 256-thread block
    for (int l = 0; l < 3; ++l) {
        if (l == 0)
            k_matmul_mfma<false><<<mmBlocks, 256, 0, stream>>>(
                in, L[l].W, dinv, stats, nullptr, nullptr, inv_n, bufA, n);
        else
            k_matmul_mfma<true><<<mmBlocks, 256, 0, stream>>>(
                in, L[l].W, dinv, stats, L[l - 1].g, L[l - 1].be, inv_n, bufA, n);
        k_gather<<<gatherBlocks, 256, 0, stream>>>(bufA, csr_src, row_ptr, dinv,
                                                   L[l].b, bufB, n);
        hipMemsetAsync(stats, 0, 2 * DIM * sizeof(float), stream);
        k_stats<<<(n + 127) / 128, 128, 0, stream>>>(bufB, stats, n);
        in = bufB;
    }

    // global mean pool + fused layer-3 BN (affine-of-mean)
    k_pool_bn<<<G, 128, 0, stream>>>(bufB, batch, stats, g2, be2, out, n, inv_n);
}

// Round 6
// 432.327 us; speedup vs baseline: 4.6732x; 1.1755x over previous
//
#include <hip/hip_runtime.h>

#define DIM 128
constexpr float EPS = 1e-5f;

typedef __attribute__((ext_vector_type(8))) __bf16 bf16x8;
typedef __attribute__((ext_vector_type(4))) float f32x4;

// ---------------- degree (int) ----------------
__global__ void k_count_deg(const int* __restrict__ dst, int* __restrict__ degi, int E) {
    int e = blockIdx.x * blockDim.x + threadIdx.x;
    if (e < E) atomicAdd(&degi[dst[e]], 1);
}

__global__ void k_dinv(const int* __restrict__ degi, float* __restrict__ dinv, int n) {
    int i = blockIdx.x * blockDim.x + threadIdx.x;
    if (i < n) dinv[i] = rsqrtf((float)degi[i] + 1.0f);
}

// ---------------- exclusive scan of degi -> row_ptr (single block) ----------------
__global__ __launch_bounds__(1024) void k_scan(const int* __restrict__ degi,
                                               int* __restrict__ row_ptr, int n) {
    __shared__ int ws[16];
    __shared__ int carry;
    if (threadIdx.x == 0) carry = 0;
    __syncthreads();
    int lane = threadIdx.x & 63;
    int wv = threadIdx.x >> 6;  // 0..15
    for (int base = 0; base < n; base += 1024) {
        int i = base + threadIdx.x;
        int v = (i < n) ? degi[i] : 0;
        int sc = v;
#pragma unroll
        for (int off = 1; off < 64; off <<= 1) {
            int t = __shfl_up(sc, off, 64);
            if (lane >= off) sc += t;
        }
        if (lane == 63) ws[wv] = sc;
        __syncthreads();
        if (threadIdx.x < 16) {
            int t = ws[threadIdx.x];
#pragma unroll
            for (int off = 1; off < 16; off <<= 1) {
                int u = __shfl_up(t, off, 64);
                if ((int)threadIdx.x >= off) t += u;
            }
            ws[threadIdx.x] = t;  // inclusive over wave sums
        }
        __syncthreads();
        int waveoff = (wv > 0) ? ws[wv - 1] : 0;
        if (i < n) row_ptr[i] = carry + waveoff + sc - v;  // exclusive
        __syncthreads();
        if (threadIdx.x == 0) carry += ws[15];
        __syncthreads();
    }
    if (threadIdx.x == 0) row_ptr[n] = carry;
}

__global__ void k_copy_int(const int* __restrict__ a, int* __restrict__ b, int n) {
    int i = blockIdx.x * blockDim.x + threadIdx.x;
    if (i < n) b[i] = a[i];
}

// ---------------- fill CSR: csr_src grouped by dst ----------------
__global__ void k_fill(const int* __restrict__ src, const int* __restrict__ dst,
                       int* __restrict__ cursor, int* __restrict__ csr_src, int E) {
    int e = blockIdx.x * blockDim.x + threadIdx.x;
    if (e >= E) return;
    int d = dst[e];
    int slot = atomicAdd(&cursor[d], 1);
    csr_src[slot] = src[e];
}

// ---------------- MFMA GEMM (bf16x3 split precision) ----------------
template <bool PRE_BN>
__global__ __launch_bounds__(256) void k_matmul_mfma(
    const float* __restrict__ in, const float* __restrict__ W,
    const float* __restrict__ dinv, const float* __restrict__ stats,
    const float* __restrict__ g, const float* __restrict__ be,
    float inv_n, float* __restrict__ out, int n) {
    __shared__ __align__(16) char sAhi[64 * 256];  // 64 rows x 128 bf16
    __shared__ __align__(16) char sAlo[64 * 256];
    __shared__ float sScale[DIM], sShift[DIM];

    int t = threadIdx.x;
    int w = t >> 6, l = t & 63;
    int row0 = blockIdx.x * 64;

    if (PRE_BN) {
        if (t < DIM) {
            float mu = stats[t] * inv_n;
            float var = stats[DIM + t] * inv_n - mu * mu;
            float sc = rsqrtf(var + EPS) * g[t];
            sScale[t] = sc;
            sShift[t] = be[t] - mu * sc;
        }
        __syncthreads();
    }

    // ---- B (W) fragments in registers: hi/lo bf16 ----
    bf16x8 bh[2][4], bl[2][4];
    {
        int col = w * 32 + (l & 15);
        int ksub = (l >> 4) * 8;
#pragma unroll
        for (int ct = 0; ct < 2; ++ct) {
            int c2 = col + ct * 16;
#pragma unroll
            for (int kt = 0; kt < 4; ++kt) {
                bf16x8 h8, l8;
#pragma unroll
                for (int j = 0; j < 8; ++j) {
                    float wv = W[(size_t)(kt * 32 + ksub + j) * DIM + c2];
                    __bf16 hv = (__bf16)wv;
                    h8[j] = hv;
                    l8[j] = (__bf16)(wv - (float)hv);
                }
                bh[ct][kt] = h8;
                bl[ct][kt] = l8;
            }
        }
    }

    // ---- stage A tile (64x128) as hi/lo bf16, XOR-swizzled ----
    {
        int r = t >> 2;
        int row_g = row0 + r;
        if (row_g >= n) row_g = n - 1;
        const float* src = in + (size_t)row_g * DIM + (t & 3) * 32;
#pragma unroll
        for (int o = 0; o < 4; ++o) {
            float4 v0 = *(const float4*)(src + o * 8);
            float4 v1 = *(const float4*)(src + o * 8 + 4);
            float vv[8] = {v0.x, v0.y, v0.z, v0.w, v1.x, v1.y, v1.z, v1.w};
            bf16x8 h8, l8;
            int c0 = (t & 3) * 32 + o * 8;
#pragma unroll
            for (int j = 0; j < 8; ++j) {
                float v = vv[j];
                if (PRE_BN) v = fmaxf(v * sScale[c0 + j] + sShift[c0 + j], 0.f);
                __bf16 hv = (__bf16)v;
                h8[j] = hv;
                l8[j] = (__bf16)(v - (float)hv);
            }
            int byte = (r * 256 + (t & 3) * 64 + o * 16) ^ ((r & 7) << 4);
            *(bf16x8*)(sAhi + byte) = h8;
            *(bf16x8*)(sAlo + byte) = l8;
        }
    }
    __syncthreads();

    // ---- MFMA main ----
    f32x4 acc[4][2];
#pragma unroll
    for (int rt = 0; rt < 4; ++rt)
#pragma unroll
        for (int ct = 0; ct < 2; ++ct) acc[rt][ct] = (f32x4){0.f, 0.f, 0.f, 0.f};

#pragma unroll
    for (int rt = 0; rt < 4; ++rt) {
        int row_l = rt * 16 + (l & 15);
        int kb = (l >> 4) * 16;
        bf16x8 ah[4], al[4];
#pragma unroll
        for (int kt = 0; kt < 4; ++kt) {
            int byte = (row_l * 256 + kt * 64 + kb) ^ ((row_l & 7) << 4);
            ah[kt] = *(const bf16x8*)(sAhi + byte);
            al[kt] = *(const bf16x8*)(sAlo + byte);
        }
#pragma unroll
        for (int ct = 0; ct < 2; ++ct) {
            f32x4 c = acc[rt][ct];
#pragma unroll
            for (int kt = 0; kt < 4; ++kt) {
                c = __builtin_amdgcn_mfma_f32_16x16x32_bf16(ah[kt], bh[ct][kt], c, 0, 0, 0);
                c = __builtin_amdgcn_mfma_f32_16x16x32_bf16(ah[kt], bl[ct][kt], c, 0, 0, 0);
                c = __builtin_amdgcn_mfma_f32_16x16x32_bf16(al[kt], bh[ct][kt], c, 0, 0, 0);
            }
            acc[rt][ct] = c;
        }
    }

    // ---- epilogue: scale by dinv[row], store ----
    int colw = w * 32 + (l & 15);
#pragma unroll
    for (int rt = 0; rt < 4; ++rt) {
        int row_l = rt * 16 + ((l >> 4) << 2);
#pragma unroll
        for (int reg = 0; reg < 4; ++reg) {
            int gr = row0 + row_l + reg;
            if (gr >= n) continue;
            float dv = dinv[gr];
#pragma unroll
            for (int ct = 0; ct < 2; ++ct)
                out[(size_t)gr * DIM + colw + ct * 16] = acc[rt][ct][reg] * dv;
        }
    }
}

// ---------------- gather: agg[d] = dinv[d]*(sum_e hs[src] + hs[d]) + b ----------------
__global__ __launch_bounds__(256) void k_gather(const float* __restrict__ hs,
                                                const int* __restrict__ csr_src,
                                                const int* __restrict__ row_ptr,
                                                const float* __restrict__ dinv,
                                                const float* __restrict__ b,
                                                float* __restrict__ agg, int n) {
    int node = (blockIdx.x * 256 + threadIdx.x) >> 6;
    if (node >= n) return;
    int l = threadIdx.x & 63;
    int grp = l >> 4;      // 0..3: edge-parallel group
    int c8 = (l & 15) * 8; // 8 channels per lane

    f32x4 acc0 = {0.f, 0.f, 0.f, 0.f}, acc1 = {0.f, 0.f, 0.f, 0.f};
    int beg = row_ptr[node], end = row_ptr[node + 1];

    int e = beg + grp;
    for (; e + 4 < end; e += 8) {
        int s0 = csr_src[e];
        int s1 = csr_src[e + 4];
        const float* p0 = hs + (size_t)s0 * DIM + c8;
        const float* p1 = hs + (size_t)s1 * DIM + c8;
        f32x4 a0 = *(const f32x4*)p0;
        f32x4 a1 = *(const f32x4*)(p0 + 4);
        f32x4 b0 = *(const f32x4*)p1;
        f32x4 b1 = *(const f32x4*)(p1 + 4);
        acc0 += a0; acc1 += a1;
        acc0 += b0; acc1 += b1;
    }
    for (; e < end; e += 4) {
        int s0 = csr_src[e];
        const float* p0 = hs + (size_t)s0 * DIM + c8;
        acc0 += *(const f32x4*)p0;
        acc1 += *(const f32x4*)(p0 + 4);
    }

#pragma unroll
    for (int j = 0; j < 4; ++j) {
        acc0[j] += __shfl_xor(acc0[j], 16, 64);
        acc0[j] += __shfl_xor(acc0[j], 32, 64);
        acc1[j] += __shfl_xor(acc1[j], 16, 64);
        acc1[j] += __shfl_xor(acc1[j], 32, 64);
    }

    if (grp == 0) {
        const float* ps = hs + (size_t)node * DIM + c8;
        f32x4 h0 = *(const f32x4*)ps;
        f32x4 h1 = *(const f32x4*)(ps + 4);
        float dv = dinv[node];
        f32x4 bb0 = *(const f32x4*)(b + c8);
        f32x4 bb1 = *(const f32x4*)(b + c8 + 4);
        f32x4 o0 = (acc0 + h0) * dv + bb0;
        f32x4 o1 = (acc1 + h1) * dv + bb1;
        *(f32x4*)(agg + (size_t)node * DIM + c8) = o0;
        *(f32x4*)(agg + (size_t)node * DIM + c8 + 4) = o1;
    }
}

// ---------------- BN stats (+optional fused pool-sum) ----------------
// 256 threads: thread handles channels c2=(t&63)*2 over rows r0+(t>>6) step 4.
// POOL: segmented per-graph running sum flushed to gsum on boundary (batch sorted).
template <bool POOL>
__global__ __launch_bounds__(256) void k_stats2(const float* __restrict__ x,
                                                const int* __restrict__ batch,
                                                float* __restrict__ stats,
                                                float* __restrict__ gsum, int n) {
    int t = threadIdx.x;
    int c2 = (t & 63) * 2;
    int rq = t >> 6;  // 0..3
    int r0 = blockIdx.x * 128;
    int r1 = min(n, r0 + 128);

    float2 s = {0.f, 0.f}, s2 = {0.f, 0.f}, ps = {0.f, 0.f};
    int curseg = -1;
    int b0 = POOL ? batch[0] : 0;

    for (int r = r0 + rq; r < r1; r += 4) {
        float2 v = *(const float2*)&x[(size_t)r * DIM + c2];
        s.x += v.x; s.y += v.y;
        s2.x += v.x * v.x; s2.y += v.y * v.y;
        if (POOL) {
            int seg = batch[r] - b0;
            if (seg != curseg) {
                if (curseg >= 0) {
                    atomicAdd(&gsum[(size_t)curseg * DIM + c2], ps.x);
                    atomicAdd(&gsum[(size_t)curseg * DIM + c2 + 1], ps.y);
                }
                ps.x = 0.f; ps.y = 0.f;
                curseg = seg;
            }
            ps.x += v.x; ps.y += v.y;
        }
    }
    if (POOL && curseg >= 0) {
        atomicAdd(&gsum[(size_t)curseg * DIM + c2], ps.x);
        atomicAdd(&gsum[(size_t)curseg * DIM + c2 + 1], ps.y);
    }

    __shared__ float2 ls[256], lq[256];
    ls[t] = s; lq[t] = s2;
    __syncthreads();
    if (t < 64) {
#pragma unroll
        for (int j = 1; j < 4; ++j) {
            s.x += ls[t + 64 * j].x; s.y += ls[t + 64 * j].y;
            s2.x += lq[t + 64 * j].x; s2.y += lq[t + 64 * j].y;
        }
        atomicAdd(&stats[c2], s.x);
        atomicAdd(&stats[c2 + 1], s.y);
        atomicAdd(&stats[DIM + c2], s2.x);
        atomicAdd(&stats[DIM + c2 + 1], s2.y);
    }
}

// ---------------- pool finalize: out = mean*scale + shift ----------------
__global__ __launch_bounds__(128) void k_pool_fin(const float* __restrict__ gsum,
                                                  const int* __restrict__ batch,
                                                  const float* __restrict__ stats,
                                                  const float* __restrict__ g,
                                                  const float* __restrict__ be,
                                                  float* __restrict__ out,
                                                  int n, float inv_n) {
    int gseg = blockIdx.x;
    int c = threadIdx.x;
    int b0 = batch[0];
    int target = b0 + gseg;
    int lo = 0, hi = n;
    while (lo < hi) { int mid = (lo + hi) >> 1; if (batch[mid] < target) lo = mid + 1; else hi = mid; }
    int start = lo;
    lo = start; hi = n;
    while (lo < hi) { int mid = (lo + hi) >> 1; if (batch[mid] < target + 1) lo = mid + 1; else hi = mid; }
    int end = lo;
    int cnt = end - start;

    float mu = stats[c] * inv_n;
    float var = stats[DIM + c] * inv_n - mu * mu;
    float scale = rsqrtf(var + EPS) * g[c];
    float shift = be[c] - mu * scale;
    float o = 0.f;
    if (cnt > 0) o = (gsum[(size_t)gseg * DIM + c] / (float)cnt) * scale + shift;
    out[(size_t)gseg * DIM + c] = o;
}

// ---------------- launch ----------------
extern "C" void kernel_launch(void* const* d_in, const int* in_sizes, int n_in,
                              void* d_out, int out_size, void* d_ws, size_t ws_size,
                              hipStream_t stream) {
    const float* x = (const float*)d_in[0];
    const int* edge_index = (const int*)d_in[1];
    const int* batch = (const int*)d_in[3];
    const float* W1 = (const float*)d_in[4];
    const float* b1 = (const float*)d_in[5];
    const float* g1 = (const float*)d_in[6];
    const float* be1 = (const float*)d_in[7];
    const float* Wm = (const float*)d_in[8];
    const float* bm = (const float*)d_in[9];
    const float* gm = (const float*)d_in[10];
    const float* bem = (const float*)d_in[11];
    const float* W2 = (const float*)d_in[12];
    const float* b2 = (const float*)d_in[13];
    const float* g2 = (const float*)d_in[14];
    const float* be2 = (const float*)d_in[15];

    int n = in_sizes[0] / DIM;
    int E = in_sizes[1] / 2;
    int G = out_size / DIM;

    const int* srcI = edge_index;
    const int* dstI = edge_index + E;

    char* p = (char*)d_ws;
    float* bufA = (float*)p;            p += (size_t)n * DIM * 4;   // hs = (in@W)*dinv
    float* bufB = (float*)p;            p += (size_t)n * DIM * 4;   // agg / layer out
    float* dinv = (float*)p;            p += (size_t)n * 4;
    int* degi = (int*)p;                p += (size_t)n * 4;
    int* row_ptr = (int*)p;             p += (size_t)(n + 1) * 4;
    int* cursor = (int*)p;              p += (size_t)n * 4;
    int* csr_src = (int*)p;             p += (size_t)E * 4;
    float* stats = (float*)p;           p += 2 * DIM * 4;
    float* gsum = (float*)p;            p += (size_t)G * DIM * 4;

    float* out = (float*)d_out;
    float inv_n = 1.0f / (float)n;

    // ---- CSR build ----
    hipMemsetAsync(degi, 0, (size_t)n * sizeof(int), stream);
    k_count_deg<<<(E + 255) / 256, 256, 0, stream>>>(dstI, degi, E);
    k_dinv<<<(n + 255) / 256, 256, 0, stream>>>(degi, dinv, n);
    k_scan<<<1, 1024, 0, stream>>>(degi, row_ptr, n);
    k_copy_int<<<(n + 255) / 256, 256, 0, stream>>>(row_ptr, cursor, n);
    k_fill<<<(E + 255) / 256, 256, 0, stream>>>(srcI, dstI, cursor, csr_src, E);

    struct Layer { const float *W, *b, *g, *be; };
    Layer L[3] = {
        {W1, b1, g1, be1},
        {Wm, bm, gm, bem},
        {W2, b2, g2, be2},
    };

    const float* in = x;
    int mmBlocks = (n + 63) / 64;
    int gatherBlocks = (n + 3) / 4;
    int statBlocks = (n + 127) / 128;
    for (int l = 0; l < 3; ++l) {
        if (l == 0)
            k_matmul_mfma<false><<<mmBlocks, 256, 0, stream>>>(
                in, L[l].W, dinv, stats, nullptr, nullptr, inv_n, bufA, n);
        else
            k_matmul_mfma<true><<<mmBlocks, 256, 0, stream>>>(
                in, L[l].W, dinv, stats, L[l - 1].g, L[l - 1].be, inv_n, bufA, n);
        k_gather<<<gatherBlocks, 256, 0, stream>>>(bufA, csr_src, row_ptr, dinv,
                                                   L[l].b, bufB, n);
        hipMemsetAsync(stats, 0, 2 * DIM * sizeof(float), stream);
        if (l < 2) {
            k_stats2<false><<<statBlocks, 256, 0, stream>>>(bufB, batch, stats,
                                                            nullptr, n);
        } else {
            hipMemsetAsync(gsum, 0, (size_t)G * DIM * sizeof(float), stream);
            k_stats2<true><<<statBlocks, 256, 0, stream>>>(bufB, batch, stats,
                                                           gsum, n);
        }
        in = bufB;
    }

    // pool finalize: mean -> BN affine
    k_pool_fin<<<G, 128, 0, stream>>>(gsum, batch, stats, g2, be2, out, n, inv_n);
}

// Round 7
// 389.294 us; speedup vs baseline: 5.1897x; 1.1105x over previous
//
#include <hip/hip_runtime.h>

#define DIM 128
constexpr float EPS = 1e-5f;

typedef __attribute__((ext_vector_type(8))) __bf16 bf16x8;
typedef __attribute__((ext_vector_type(4))) float f32x4;

// ---------------- degree (int) ----------------
__global__ void k_count_deg(const int* __restrict__ dst, int* __restrict__ degi, int E) {
    int e = blockIdx.x * blockDim.x + threadIdx.x;
    if (e < E) atomicAdd(&degi[dst[e]], 1);
}

// ---------------- multi-block exclusive scan of degi -> row_ptr ----------------
// Pass 1: block-local exclusive scan (1024 elems/block) + fused dinv.
__global__ __launch_bounds__(256) void k_scan_local(const int* __restrict__ degi,
                                                    int* __restrict__ row_ptr,
                                                    float* __restrict__ dinv,
                                                    int* __restrict__ bsum, int n) {
    __shared__ int ws[4];
    int t = threadIdx.x, lane = t & 63, wv = t >> 6;
    int i0 = blockIdx.x * 1024 + t * 4;
    int v[4];
#pragma unroll
    for (int j = 0; j < 4; ++j) {
        int i = i0 + j;
        v[j] = (i < n) ? degi[i] : 0;
        if (i < n) dinv[i] = rsqrtf((float)v[j] + 1.0f);
    }
    int tsum = v[0] + v[1] + v[2] + v[3];
    int sc = tsum;
#pragma unroll
    for (int off = 1; off < 64; off <<= 1) {
        int u = __shfl_up(sc, off, 64);
        if (lane >= off) sc += u;
    }
    if (lane == 63) ws[wv] = sc;
    __syncthreads();
    int woff = 0;
    for (int j = 0; j < wv; ++j) woff += ws[j];
    int run = woff + sc - tsum;  // exclusive prefix within block
#pragma unroll
    for (int j = 0; j < 4; ++j) {
        int i = i0 + j;
        if (i < n) row_ptr[i] = run;
        run += v[j];
    }
    if (t == 255) bsum[blockIdx.x] = woff + sc;  // block total
}

// Pass 2: exclusive scan of block sums (single wave; nb <= 64).
__global__ void k_scan_bsums(int* __restrict__ bsum, int nb) {
    int l = threadIdx.x;
    int v = (l < nb) ? bsum[l] : 0;
    int sc = v;
#pragma unroll
    for (int off = 1; off < 64; off <<= 1) {
        int u = __shfl_up(sc, off, 64);
        if (l >= off) sc += u;
    }
    if (l < nb) bsum[l] = sc - v;  // exclusive
}

// Pass 3: add block offsets; fused cursor init; row_ptr[n] = E.
__global__ void k_scan_add(int* __restrict__ row_ptr, int* __restrict__ cursor,
                           const int* __restrict__ bsum, int n, int E) {
    int i = blockIdx.x * blockDim.x + threadIdx.x;
    if (i < n) {
        int v = row_ptr[i] + bsum[i >> 10];
        row_ptr[i] = v;
        cursor[i] = v;
    }
    if (i == 0) row_ptr[n] = E;
}

// ---------------- fill CSR: csr_src grouped by dst ----------------
__global__ void k_fill(const int* __restrict__ src, const int* __restrict__ dst,
                       int* __restrict__ cursor, int* __restrict__ csr_src, int E) {
    int e = blockIdx.x * blockDim.x + threadIdx.x;
    if (e >= E) return;
    int d = dst[e];
    int slot = atomicAdd(&cursor[d], 1);
    csr_src[slot] = src[e];
}

// ---------------- MFMA GEMM (bf16x3 split precision) ----------------
template <bool PRE_BN>
__global__ __launch_bounds__(256) void k_matmul_mfma(
    const float* __restrict__ in, const float* __restrict__ W,
    const float* __restrict__ dinv, const float* __restrict__ stats,
    const float* __restrict__ g, const float* __restrict__ be,
    float inv_n, float* __restrict__ out, int n) {
    __shared__ __align__(16) char sAhi[64 * 256];  // 64 rows x 128 bf16
    __shared__ __align__(16) char sAlo[64 * 256];
    __shared__ float sScale[DIM], sShift[DIM];

    int t = threadIdx.x;
    int w = t >> 6, l = t & 63;
    int row0 = blockIdx.x * 64;

    if (PRE_BN) {
        if (t < DIM) {
            float mu = stats[t] * inv_n;
            float var = stats[DIM + t] * inv_n - mu * mu;
            float sc = rsqrtf(var + EPS) * g[t];
            sScale[t] = sc;
            sShift[t] = be[t] - mu * sc;
        }
        __syncthreads();
    }

    // ---- B (W) fragments in registers: hi/lo bf16 ----
    bf16x8 bh[2][4], bl[2][4];
    {
        int col = w * 32 + (l & 15);
        int ksub = (l >> 4) * 8;
#pragma unroll
        for (int ct = 0; ct < 2; ++ct) {
            int c2 = col + ct * 16;
#pragma unroll
            for (int kt = 0; kt < 4; ++kt) {
                bf16x8 h8, l8;
#pragma unroll
                for (int j = 0; j < 8; ++j) {
                    float wv = W[(size_t)(kt * 32 + ksub + j) * DIM + c2];
                    __bf16 hv = (__bf16)wv;
                    h8[j] = hv;
                    l8[j] = (__bf16)(wv - (float)hv);
                }
                bh[ct][kt] = h8;
                bl[ct][kt] = l8;
            }
        }
    }

    // ---- stage A tile (64x128) as hi/lo bf16, XOR-swizzled ----
    {
        int r = t >> 2;
        int row_g = row0 + r;
        if (row_g >= n) row_g = n - 1;
        const float* src = in + (size_t)row_g * DIM + (t & 3) * 32;
#pragma unroll
        for (int o = 0; o < 4; ++o) {
            float4 v0 = *(const float4*)(src + o * 8);
            float4 v1 = *(const float4*)(src + o * 8 + 4);
            float vv[8] = {v0.x, v0.y, v0.z, v0.w, v1.x, v1.y, v1.z, v1.w};
            bf16x8 h8, l8;
            int c0 = (t & 3) * 32 + o * 8;
#pragma unroll
            for (int j = 0; j < 8; ++j) {
                float v = vv[j];
                if (PRE_BN) v = fmaxf(v * sScale[c0 + j] + sShift[c0 + j], 0.f);
                __bf16 hv = (__bf16)v;
                h8[j] = hv;
                l8[j] = (__bf16)(v - (float)hv);
            }
            int byte = (r * 256 + (t & 3) * 64 + o * 16) ^ ((r & 7) << 4);
            *(bf16x8*)(sAhi + byte) = h8;
            *(bf16x8*)(sAlo + byte) = l8;
        }
    }
    __syncthreads();

    // ---- MFMA main ----
    f32x4 acc[4][2];
#pragma unroll
    for (int rt = 0; rt < 4; ++rt)
#pragma unroll
        for (int ct = 0; ct < 2; ++ct) acc[rt][ct] = (f32x4){0.f, 0.f, 0.f, 0.f};

#pragma unroll
    for (int rt = 0; rt < 4; ++rt) {
        int row_l = rt * 16 + (l & 15);
        int kb = (l >> 4) * 16;
        bf16x8 ah[4], al[4];
#pragma unroll
        for (int kt = 0; kt < 4; ++kt) {
            int byte = (row_l * 256 + kt * 64 + kb) ^ ((row_l & 7) << 4);
            ah[kt] = *(const bf16x8*)(sAhi + byte);
            al[kt] = *(const bf16x8*)(sAlo + byte);
        }
#pragma unroll
        for (int ct = 0; ct < 2; ++ct) {
            f32x4 c = acc[rt][ct];
#pragma unroll
            for (int kt = 0; kt < 4; ++kt) {
                c = __builtin_amdgcn_mfma_f32_16x16x32_bf16(ah[kt], bh[ct][kt], c, 0, 0, 0);
                c = __builtin_amdgcn_mfma_f32_16x16x32_bf16(ah[kt], bl[ct][kt], c, 0, 0, 0);
                c = __builtin_amdgcn_mfma_f32_16x16x32_bf16(al[kt], bh[ct][kt], c, 0, 0, 0);
            }
            acc[rt][ct] = c;
        }
    }

    // ---- epilogue: scale by dinv[row], store ----
    int colw = w * 32 + (l & 15);
#pragma unroll
    for (int rt = 0; rt < 4; ++rt) {
        int row_l = rt * 16 + ((l >> 4) << 2);
#pragma unroll
        for (int reg = 0; reg < 4; ++reg) {
            int gr = row0 + row_l + reg;
            if (gr >= n) continue;
            float dv = dinv[gr];
#pragma unroll
            for (int ct = 0; ct < 2; ++ct)
                out[(size_t)gr * DIM + colw + ct * 16] = acc[rt][ct][reg] * dv;
        }
    }
}

// ---------------- gather: agg[d] = dinv[d]*(sum_e hs[src] + hs[d]) + b ----------------
__global__ __launch_bounds__(256) void k_gather(const float* __restrict__ hs,
                                                const int* __restrict__ csr_src,
                                                const int* __restrict__ row_ptr,
                                                const float* __restrict__ dinv,
                                                const float* __restrict__ b,
                                                float* __restrict__ agg, int n) {
    int node = (blockIdx.x * 256 + threadIdx.x) >> 6;
    if (node >= n) return;
    int l = threadIdx.x & 63;
    int grp = l >> 4;      // 0..3: edge-parallel group
    int c8 = (l & 15) * 8; // 8 channels per lane

    f32x4 acc0 = {0.f, 0.f, 0.f, 0.f}, acc1 = {0.f, 0.f, 0.f, 0.f};
    int beg = row_ptr[node], end = row_ptr[node + 1];

    int e = beg + grp;
    for (; e + 4 < end; e += 8) {
        int s0 = csr_src[e];
        int s1 = csr_src[e + 4];
        const float* p0 = hs + (size_t)s0 * DIM + c8;
        const float* p1 = hs + (size_t)s1 * DIM + c8;
        f32x4 a0 = *(const f32x4*)p0;
        f32x4 a1 = *(const f32x4*)(p0 + 4);
        f32x4 b0 = *(const f32x4*)p1;
        f32x4 b1 = *(const f32x4*)(p1 + 4);
        acc0 += a0; acc1 += a1;
        acc0 += b0; acc1 += b1;
    }
    for (; e < end; e += 4) {
        int s0 = csr_src[e];
        const float* p0 = hs + (size_t)s0 * DIM + c8;
        acc0 += *(const f32x4*)p0;
        acc1 += *(const f32x4*)(p0 + 4);
    }

#pragma unroll
    for (int j = 0; j < 4; ++j) {
        acc0[j] += __shfl_xor(acc0[j], 16, 64);
        acc0[j] += __shfl_xor(acc0[j], 32, 64);
        acc1[j] += __shfl_xor(acc1[j], 16, 64);
        acc1[j] += __shfl_xor(acc1[j], 32, 64);
    }

    if (grp == 0) {
        const float* ps = hs + (size_t)node * DIM + c8;
        f32x4 h0 = *(const f32x4*)ps;
        f32x4 h1 = *(const f32x4*)(ps + 4);
        float dv = dinv[node];
        f32x4 bb0 = *(const f32x4*)(b + c8);
        f32x4 bb1 = *(const f32x4*)(b + c8 + 4);
        f32x4 o0 = (acc0 + h0) * dv + bb0;
        f32x4 o1 = (acc1 + h1) * dv + bb1;
        *(f32x4*)(agg + (size_t)node * DIM + c8) = o0;
        *(f32x4*)(agg + (size_t)node * DIM + c8 + 4) = o1;
    }
}

// ---------------- BN stats (+optional fused pool-sum) ----------------
template <bool POOL>
__global__ __launch_bounds__(256) void k_stats2(const float* __restrict__ x,
                                                const int* __restrict__ batch,
                                                float* __restrict__ stats,
                                                float* __restrict__ gsum, int n) {
    int t = threadIdx.x;
    int c2 = (t & 63) * 2;
    int rq = t >> 6;  // 0..3
    int r0 = blockIdx.x * 128;
    int r1 = min(n, r0 + 128);

    float2 s = {0.f, 0.f}, s2 = {0.f, 0.f}, ps = {0.f, 0.f};
    int curseg = -1;
    int b0 = POOL ? batch[0] : 0;

    for (int r = r0 + rq; r < r1; r += 4) {
        float2 v = *(const float2*)&x[(size_t)r * DIM + c2];
        s.x += v.x; s.y += v.y;
        s2.x += v.x * v.x; s2.y += v.y * v.y;
        if (POOL) {
            int seg = batch[r] - b0;
            if (seg != curseg) {
                if (curseg >= 0) {
                    atomicAdd(&gsum[(size_t)curseg * DIM + c2], ps.x);
                    atomicAdd(&gsum[(size_t)curseg * DIM + c2 + 1], ps.y);
                }
                ps.x = 0.f; ps.y = 0.f;
                curseg = seg;
            }
            ps.x += v.x; ps.y += v.y;
        }
    }
    if (POOL && curseg >= 0) {
        atomicAdd(&gsum[(size_t)curseg * DIM + c2], ps.x);
        atomicAdd(&gsum[(size_t)curseg * DIM + c2 + 1], ps.y);
    }

    __shared__ float2 ls[256], lq[256];
    ls[t] = s; lq[t] = s2;
    __syncthreads();
    if (t < 64) {
#pragma unroll
        for (int j = 1; j < 4; ++j) {
            s.x += ls[t + 64 * j].x; s.y += ls[t + 64 * j].y;
            s2.x += lq[t + 64 * j].x; s2.y += lq[t + 64 * j].y;
        }
        atomicAdd(&stats[c2], s.x);
        atomicAdd(&stats[c2 + 1], s.y);
        atomicAdd(&stats[DIM + c2], s2.x);
        atomicAdd(&stats[DIM + c2 + 1], s2.y);
    }
}

// ---------------- pool finalize: out = mean*scale + shift ----------------
__global__ __launch_bounds__(128) void k_pool_fin(const float* __restrict__ gsum,
                                                  const int* __restrict__ batch,
                                                  const float* __restrict__ stats,
                                                  const float* __restrict__ g,
                                                  const float* __restrict__ be,
                                                  float* __restrict__ out,
                                                  int n, float inv_n) {
    int gseg = blockIdx.x;
    int c = threadIdx.x;
    int b0 = batch[0];
    int target = b0 + gseg;
    int lo = 0, hi = n;
    while (lo < hi) { int mid = (lo + hi) >> 1; if (batch[mid] < target) lo = mid + 1; else hi = mid; }
    int start = lo;
    lo = start; hi = n;
    while (lo < hi) { int mid = (lo + hi) >> 1; if (batch[mid] < target + 1) lo = mid + 1; else hi = mid; }
    int end = lo;
    int cnt = end - start;

    float mu = stats[c] * inv_n;
    float var = stats[DIM + c] * inv_n - mu * mu;
    float scale = rsqrtf(var + EPS) * g[c];
    float shift = be[c] - mu * scale;
    float o = 0.f;
    if (cnt > 0) o = (gsum[(size_t)gseg * DIM + c] / (float)cnt) * scale + shift;
    out[(size_t)gseg * DIM + c] = o;
}

// ---------------- launch ----------------
extern "C" void kernel_launch(void* const* d_in, const int* in_sizes, int n_in,
                              void* d_out, int out_size, void* d_ws, size_t ws_size,
                              hipStream_t stream) {
    const float* x = (const float*)d_in[0];
    const int* edge_index = (const int*)d_in[1];
    const int* batch = (const int*)d_in[3];
    const float* W1 = (const float*)d_in[4];
    const float* b1 = (const float*)d_in[5];
    const float* g1 = (const float*)d_in[6];
    const float* be1 = (const float*)d_in[7];
    const float* Wm = (const float*)d_in[8];
    const float* bm = (const float*)d_in[9];
    const float* gm = (const float*)d_in[10];
    const float* bem = (const float*)d_in[11];
    const float* W2 = (const float*)d_in[12];
    const float* b2 = (const float*)d_in[13];
    const float* g2 = (const float*)d_in[14];
    const float* be2 = (const float*)d_in[15];

    int n = in_sizes[0] / DIM;
    int E = in_sizes[1] / 2;
    int G = out_size / DIM;

    const int* srcI = edge_index;
    const int* dstI = edge_index + E;

    char* p = (char*)d_ws;
    float* bufA = (float*)p;            p += (size_t)n * DIM * 4;   // hs = (in@W)*dinv
    float* bufB = (float*)p;            p += (size_t)n * DIM * 4;   // agg / layer out
    float* dinv = (float*)p;            p += (size_t)n * 4;
    int* degi = (int*)p;                p += (size_t)n * 4;
    int* row_ptr = (int*)p;             p += (size_t)(n + 1) * 4;
    int* cursor = (int*)p;              p += (size_t)n * 4;
    int* csr_src = (int*)p;             p += (size_t)E * 4;
    float* stats = (float*)p;           p += 2 * DIM * 4;
    float* gsum = (float*)p;            p += (size_t)G * DIM * 4;
    int* bsum = (int*)p;                p += 64 * 4;

    float* out = (float*)d_out;
    float inv_n = 1.0f / (float)n;
    int nb = (n + 1023) / 1024;  // blocks in scan pass (<=64 for n<=65536)

    // ---- CSR build ----
    hipMemsetAsync(degi, 0, (size_t)n * sizeof(int), stream);
    k_count_deg<<<(E + 255) / 256, 256, 0, stream>>>(dstI, degi, E);
    k_scan_local<<<nb, 256, 0, stream>>>(degi, row_ptr, dinv, bsum, n);
    k_scan_bsums<<<1, 64, 0, stream>>>(bsum, nb);
    k_scan_add<<<(n + 255) / 256, 256, 0, stream>>>(row_ptr, cursor, bsum, n, E);
    k_fill<<<(E + 255) / 256, 256, 0, stream>>>(srcI, dstI, cursor, csr_src, E);

    struct Layer { const float *W, *b, *g, *be; };
    Layer L[3] = {
        {W1, b1, g1, be1},
        {Wm, bm, gm, bem},
        {W2, b2, g2, be2},
    };

    const float* in = x;
    int mmBlocks = (n + 63) / 64;
    int gatherBlocks = (n + 3) / 4;
    int statBlocks = (n + 127) / 128;
    for (int l = 0; l < 3; ++l) {
        if (l == 0)
            k_matmul_mfma<false><<<mmBlocks, 256, 0, stream>>>(
                in, L[l].W, dinv, stats, nullptr, nullptr, inv_n, bufA, n);
        else
            k_matmul_mfma<true><<<mmBlocks, 256, 0, stream>>>(
                in, L[l].W, dinv, stats, L[l - 1].g, L[l - 1].be, inv_n, bufA, n);
        k_gather<<<gatherBlocks, 256, 0, stream>>>(bufA, csr_src, row_ptr, dinv,
                                                   L[l].b, bufB, n);
        hipMemsetAsync(stats, 0, 2 * DIM * sizeof(float), stream);
        if (l < 2) {
            k_stats2<false><<<statBlocks, 256, 0, stream>>>(bufB, batch, stats,
                                                            nullptr, n);
        } else {
            hipMemsetAsync(gsum, 0, (size_t)G * DIM * sizeof(float), stream);
            k_stats2<true><<<statBlocks, 256, 0, stream>>>(bufB, batch, stats,
                                                           gsum, n);
        }
        in = bufB;
    }

    // pool finalize: mean -> BN affine
    k_pool_fin<<<G, 128, 0, stream>>>(gsum, batch, stats, g2, be2, out, n, inv_n);
}

// Round 8
// 345.834 us; speedup vs baseline: 5.8419x; 1.1257x over previous
//
#include <hip/hip_runtime.h>

#define DIM 128
constexpr float EPS = 1e-5f;

typedef __attribute__((ext_vector_type(8))) __bf16 bf16x8;
typedef __attribute__((ext_vector_type(4))) float f32x4;
typedef _Float16 f16;
typedef __attribute__((ext_vector_type(8))) _Float16 f16x8;

// ---------------- degree (int) ----------------
__global__ void k_count_deg(const int* __restrict__ dst, int* __restrict__ degi, int E) {
    int e = blockIdx.x * blockDim.x + threadIdx.x;
    if (e < E) atomicAdd(&degi[dst[e]], 1);
}

// ---------------- multi-block exclusive scan of degi -> row_ptr ----------------
__global__ __launch_bounds__(256) void k_scan_local(const int* __restrict__ degi,
                                                    int* __restrict__ row_ptr,
                                                    float* __restrict__ dinv,
                                                    int* __restrict__ bsum, int n) {
    __shared__ int ws[4];
    int t = threadIdx.x, lane = t & 63, wv = t >> 6;
    int i0 = blockIdx.x * 1024 + t * 4;
    int v[4];
#pragma unroll
    for (int j = 0; j < 4; ++j) {
        int i = i0 + j;
        v[j] = (i < n) ? degi[i] : 0;
        if (i < n) dinv[i] = rsqrtf((float)v[j] + 1.0f);
    }
    int tsum = v[0] + v[1] + v[2] + v[3];
    int sc = tsum;
#pragma unroll
    for (int off = 1; off < 64; off <<= 1) {
        int u = __shfl_up(sc, off, 64);
        if (lane >= off) sc += u;
    }
    if (lane == 63) ws[wv] = sc;
    __syncthreads();
    int woff = 0;
    for (int j = 0; j < wv; ++j) woff += ws[j];
    int run = woff + sc - tsum;
#pragma unroll
    for (int j = 0; j < 4; ++j) {
        int i = i0 + j;
        if (i < n) row_ptr[i] = run;
        run += v[j];
    }
    if (t == 255) bsum[blockIdx.x] = woff + sc;
}

__global__ void k_scan_bsums(int* __restrict__ bsum, int nb) {
    int l = threadIdx.x;
    int v = (l < nb) ? bsum[l] : 0;
    int sc = v;
#pragma unroll
    for (int off = 1; off < 64; off <<= 1) {
        int u = __shfl_up(sc, off, 64);
        if (l >= off) sc += u;
    }
    if (l < nb) bsum[l] = sc - v;
}

__global__ void k_scan_add(int* __restrict__ row_ptr, int* __restrict__ cursor,
                           const int* __restrict__ bsum, int n, int E) {
    int i = blockIdx.x * blockDim.x + threadIdx.x;
    if (i < n) {
        int v = row_ptr[i] + bsum[i >> 10];
        row_ptr[i] = v;
        cursor[i] = v;
    }
    if (i == 0) row_ptr[n] = E;
}

// ---------------- fill CSR: csr_src grouped by dst ----------------
__global__ void k_fill(const int* __restrict__ src, const int* __restrict__ dst,
                       int* __restrict__ cursor, int* __restrict__ csr_src, int E) {
    int e = blockIdx.x * blockDim.x + threadIdx.x;
    if (e >= E) return;
    int d = dst[e];
    int slot = atomicAdd(&cursor[d], 1);
    csr_src[slot] = src[e];
}

// ---------------- MFMA GEMM (bf16x3 split precision), fp16 output ----------------
template <bool PRE_BN>
__global__ __launch_bounds__(256) void k_matmul_mfma(
    const float* __restrict__ in, const float* __restrict__ W,
    const float* __restrict__ dinv, const float* __restrict__ stats,
    const float* __restrict__ g, const float* __restrict__ be,
    float inv_n, f16* __restrict__ out, int n) {
    __shared__ __align__(16) char sAhi[64 * 256];  // 64 rows x 128 bf16
    __shared__ __align__(16) char sAlo[64 * 256];
    __shared__ float sScale[DIM], sShift[DIM];

    int t = threadIdx.x;
    int w = t >> 6, l = t & 63;
    int row0 = blockIdx.x * 64;

    if (PRE_BN) {
        if (t < DIM) {
            float mu = stats[t] * inv_n;
            float var = stats[DIM + t] * inv_n - mu * mu;
            float sc = rsqrtf(var + EPS) * g[t];
            sScale[t] = sc;
            sShift[t] = be[t] - mu * sc;
        }
        __syncthreads();
    }

    // ---- B (W) fragments in registers: hi/lo bf16 ----
    bf16x8 bh[2][4], bl[2][4];
    {
        int col = w * 32 + (l & 15);
        int ksub = (l >> 4) * 8;
#pragma unroll
        for (int ct = 0; ct < 2; ++ct) {
            int c2 = col + ct * 16;
#pragma unroll
            for (int kt = 0; kt < 4; ++kt) {
                bf16x8 h8, l8;
#pragma unroll
                for (int j = 0; j < 8; ++j) {
                    float wv = W[(size_t)(kt * 32 + ksub + j) * DIM + c2];
                    __bf16 hv = (__bf16)wv;
                    h8[j] = hv;
                    l8[j] = (__bf16)(wv - (float)hv);
                }
                bh[ct][kt] = h8;
                bl[ct][kt] = l8;
            }
        }
    }

    // ---- stage A tile (64x128) as hi/lo bf16, XOR-swizzled ----
    {
        int r = t >> 2;
        int row_g = row0 + r;
        if (row_g >= n) row_g = n - 1;
        const float* src = in + (size_t)row_g * DIM + (t & 3) * 32;
#pragma unroll
        for (int o = 0; o < 4; ++o) {
            float4 v0 = *(const float4*)(src + o * 8);
            float4 v1 = *(const float4*)(src + o * 8 + 4);
            float vv[8] = {v0.x, v0.y, v0.z, v0.w, v1.x, v1.y, v1.z, v1.w};
            bf16x8 h8, l8;
            int c0 = (t & 3) * 32 + o * 8;
#pragma unroll
            for (int j = 0; j < 8; ++j) {
                float v = vv[j];
                if (PRE_BN) v = fmaxf(v * sScale[c0 + j] + sShift[c0 + j], 0.f);
                __bf16 hv = (__bf16)v;
                h8[j] = hv;
                l8[j] = (__bf16)(v - (float)hv);
            }
            int byte = (r * 256 + (t & 3) * 64 + o * 16) ^ ((r & 7) << 4);
            *(bf16x8*)(sAhi + byte) = h8;
            *(bf16x8*)(sAlo + byte) = l8;
        }
    }
    __syncthreads();

    // ---- MFMA main ----
    f32x4 acc[4][2];
#pragma unroll
    for (int rt = 0; rt < 4; ++rt)
#pragma unroll
        for (int ct = 0; ct < 2; ++ct) acc[rt][ct] = (f32x4){0.f, 0.f, 0.f, 0.f};

#pragma unroll
    for (int rt = 0; rt < 4; ++rt) {
        int row_l = rt * 16 + (l & 15);
        int kb = (l >> 4) * 16;
        bf16x8 ah[4], al[4];
#pragma unroll
        for (int kt = 0; kt < 4; ++kt) {
            int byte = (row_l * 256 + kt * 64 + kb) ^ ((row_l & 7) << 4);
            ah[kt] = *(const bf16x8*)(sAhi + byte);
            al[kt] = *(const bf16x8*)(sAlo + byte);
        }
#pragma unroll
        for (int ct = 0; ct < 2; ++ct) {
            f32x4 c = acc[rt][ct];
#pragma unroll
            for (int kt = 0; kt < 4; ++kt) {
                c = __builtin_amdgcn_mfma_f32_16x16x32_bf16(ah[kt], bh[ct][kt], c, 0, 0, 0);
                c = __builtin_amdgcn_mfma_f32_16x16x32_bf16(ah[kt], bl[ct][kt], c, 0, 0, 0);
                c = __builtin_amdgcn_mfma_f32_16x16x32_bf16(al[kt], bh[ct][kt], c, 0, 0, 0);
            }
            acc[rt][ct] = c;
        }
    }

    // ---- epilogue: scale by dinv[row], store fp16 ----
    int colw = w * 32 + (l & 15);
#pragma unroll
    for (int rt = 0; rt < 4; ++rt) {
        int row_l = rt * 16 + ((l >> 4) << 2);
#pragma unroll
        for (int reg = 0; reg < 4; ++reg) {
            int gr = row0 + row_l + reg;
            if (gr >= n) continue;
            float dv = dinv[gr];
#pragma unroll
            for (int ct = 0; ct < 2; ++ct)
                out[(size_t)gr * DIM + colw + ct * 16] = (f16)(acc[rt][ct][reg] * dv);
        }
    }
}

// ---------------- gather (fp16 source): agg[d] = dinv[d]*(sum_e hs[src] + hs[d]) + b --
__global__ __launch_bounds__(256) void k_gather(const f16* __restrict__ hs,
                                                const int* __restrict__ csr_src,
                                                const int* __restrict__ row_ptr,
                                                const float* __restrict__ dinv,
                                                const float* __restrict__ b,
                                                float* __restrict__ agg, int n) {
    int node = (blockIdx.x * 256 + threadIdx.x) >> 6;
    if (node >= n) return;
    int l = threadIdx.x & 63;
    int grp = l >> 4;      // 0..3: edge-parallel group
    int c8 = (l & 15) * 8; // 8 channels per lane (16 B fp16)

    float acc[8] = {};
    int beg = row_ptr[node], end = row_ptr[node + 1];

    int e = beg + grp;
    for (; e + 4 < end; e += 8) {
        int s0 = csr_src[e];
        int s1 = csr_src[e + 4];
        f16x8 a = *(const f16x8*)(hs + (size_t)s0 * DIM + c8);
        f16x8 c = *(const f16x8*)(hs + (size_t)s1 * DIM + c8);
#pragma unroll
        for (int j = 0; j < 8; ++j) acc[j] += (float)a[j] + (float)c[j];
    }
    for (; e < end; e += 4) {
        int s0 = csr_src[e];
        f16x8 a = *(const f16x8*)(hs + (size_t)s0 * DIM + c8);
#pragma unroll
        for (int j = 0; j < 8; ++j) acc[j] += (float)a[j];
    }

#pragma unroll
    for (int j = 0; j < 8; ++j) {
        acc[j] += __shfl_xor(acc[j], 16, 64);
        acc[j] += __shfl_xor(acc[j], 32, 64);
    }

    if (grp == 0) {
        f16x8 hv = *(const f16x8*)(hs + (size_t)node * DIM + c8);
        float dv = dinv[node];
        f32x4 o0, o1;
        f32x4 bb0 = *(const f32x4*)(b + c8);
        f32x4 bb1 = *(const f32x4*)(b + c8 + 4);
#pragma unroll
        for (int j = 0; j < 4; ++j) {
            o0[j] = (acc[j] + (float)hv[j]) * dv + bb0[j];
            o1[j] = (acc[j + 4] + (float)hv[j + 4]) * dv + bb1[j];
        }
        *(f32x4*)(agg + (size_t)node * DIM + c8) = o0;
        *(f32x4*)(agg + (size_t)node * DIM + c8 + 4) = o1;
    }
}

// ---------------- BN stats (+optional fused pool-sum) ----------------
template <bool POOL>
__global__ __launch_bounds__(256) void k_stats2(const float* __restrict__ x,
                                                const int* __restrict__ batch,
                                                float* __restrict__ stats,
                                                float* __restrict__ gsum, int n) {
    int t = threadIdx.x;
    int c2 = (t & 63) * 2;
    int rq = t >> 6;  // 0..3
    int r0 = blockIdx.x * 128;
    int r1 = min(n, r0 + 128);

    float2 s = {0.f, 0.f}, s2 = {0.f, 0.f}, ps = {0.f, 0.f};
    int curseg = -1;
    int b0 = POOL ? batch[0] : 0;

    for (int r = r0 + rq; r < r1; r += 4) {
        float2 v = *(const float2*)&x[(size_t)r * DIM + c2];
        s.x += v.x; s.y += v.y;
        s2.x += v.x * v.x; s2.y += v.y * v.y;
        if (POOL) {
            int seg = batch[r] - b0;
            if (seg != curseg) {
                if (curseg >= 0) {
                    atomicAdd(&gsum[(size_t)curseg * DIM + c2], ps.x);
                    atomicAdd(&gsum[(size_t)curseg * DIM + c2 + 1], ps.y);
                }
                ps.x = 0.f; ps.y = 0.f;
                curseg = seg;
            }
            ps.x += v.x; ps.y += v.y;
        }
    }
    if (POOL && curseg >= 0) {
        atomicAdd(&gsum[(size_t)curseg * DIM + c2], ps.x);
        atomicAdd(&gsum[(size_t)curseg * DIM + c2 + 1], ps.y);
    }

    __shared__ float2 ls[256], lq[256];
    ls[t] = s; lq[t] = s2;
    __syncthreads();
    if (t < 64) {
#pragma unroll
        for (int j = 1; j < 4; ++j) {
            s.x += ls[t + 64 * j].x; s.y += ls[t + 64 * j].y;
            s2.x += lq[t + 64 * j].x; s2.y += lq[t + 64 * j].y;
        }
        atomicAdd(&stats[c2], s.x);
        atomicAdd(&stats[c2 + 1], s.y);
        atomicAdd(&stats[DIM + c2], s2.x);
        atomicAdd(&stats[DIM + c2 + 1], s2.y);
    }
}

// ---------------- pool finalize: out = mean*scale + shift ----------------
__global__ __launch_bounds__(128) void k_pool_fin(const float* __restrict__ gsum,
                                                  const int* __restrict__ batch,
                                                  const float* __restrict__ stats,
                                                  const float* __restrict__ g,
                                                  const float* __restrict__ be,
                                                  float* __restrict__ out,
                                                  int n, float inv_n) {
    int gseg = blockIdx.x;
    int c = threadIdx.x;
    int b0 = batch[0];
    int target = b0 + gseg;
    int lo = 0, hi = n;
    while (lo < hi) { int mid = (lo + hi) >> 1; if (batch[mid] < target) lo = mid + 1; else hi = mid; }
    int start = lo;
    lo = start; hi = n;
    while (lo < hi) { int mid = (lo + hi) >> 1; if (batch[mid] < target + 1) lo = mid + 1; else hi = mid; }
    int end = lo;
    int cnt = end - start;

    float mu = stats[c] * inv_n;
    float var = stats[DIM + c] * inv_n - mu * mu;
    float scale = rsqrtf(var + EPS) * g[c];
    float shift = be[c] - mu * scale;
    float o = 0.f;
    if (cnt > 0) o = (gsum[(size_t)gseg * DIM + c] / (float)cnt) * scale + shift;
    out[(size_t)gseg * DIM + c] = o;
}

// ---------------- launch ----------------
extern "C" void kernel_launch(void* const* d_in, const int* in_sizes, int n_in,
                              void* d_out, int out_size, void* d_ws, size_t ws_size,
                              hipStream_t stream) {
    const float* x = (const float*)d_in[0];
    const int* edge_index = (const int*)d_in[1];
    const int* batch = (const int*)d_in[3];
    const float* W1 = (const float*)d_in[4];
    const float* b1 = (const float*)d_in[5];
    const float* g1 = (const float*)d_in[6];
    const float* be1 = (const float*)d_in[7];
    const float* Wm = (const float*)d_in[8];
    const float* bm = (const float*)d_in[9];
    const float* gm = (const float*)d_in[10];
    const float* bem = (const float*)d_in[11];
    const float* W2 = (const float*)d_in[12];
    const float* b2 = (const float*)d_in[13];
    const float* g2 = (const float*)d_in[14];
    const float* be2 = (const float*)d_in[15];

    int n = in_sizes[0] / DIM;
    int E = in_sizes[1] / 2;
    int G = out_size / DIM;

    const int* srcI = edge_index;
    const int* dstI = edge_index + E;

    char* p = (char*)d_ws;
    f16* bufA = (f16*)p;                p += (size_t)n * DIM * 2;   // hs fp16
    float* bufB = (float*)p;            p += (size_t)n * DIM * 4;   // agg / layer out
    float* dinv = (float*)p;            p += (size_t)n * 4;
    int* degi = (int*)p;                p += (size_t)n * 4;
    int* row_ptr = (int*)p;             p += (size_t)(n + 1) * 4;
    int* cursor = (int*)p;              p += (size_t)n * 4;
    int* csr_src = (int*)p;             p += (size_t)E * 4;
    float* stats = (float*)p;           p += 2 * DIM * 4;
    float* gsum = (float*)p;            p += (size_t)G * DIM * 4;
    int* bsum = (int*)p;                p += 64 * 4;

    float* out = (float*)d_out;
    float inv_n = 1.0f / (float)n;
    int nb = (n + 1023) / 1024;

    // ---- CSR build ----
    hipMemsetAsync(degi, 0, (size_t)n * sizeof(int), stream);
    k_count_deg<<<(E + 255) / 256, 256, 0, stream>>>(dstI, degi, E);
    k_scan_local<<<nb, 256, 0, stream>>>(degi, row_ptr, dinv, bsum, n);
    k_scan_bsums<<<1, 64, 0, stream>>>(bsum, nb);
    k_scan_add<<<(n + 255) / 256, 256, 0, stream>>>(row_ptr, cursor, bsum, n, E);
    k_fill<<<(E + 255) / 256, 256, 0, stream>>>(srcI, dstI, cursor, csr_src, E);

    struct Layer { const float *W, *b, *g, *be; };
    Layer L[3] = {
        {W1, b1, g1, be1},
        {Wm, bm, gm, bem},
        {W2, b2, g2, be2},
    };

    const float* in = x;
    int mmBlocks = (n + 63) / 64;
    int gatherBlocks = (n + 3) / 4;
    int statBlocks = (n + 127) / 128;
    for (int l = 0; l < 3; ++l) {
        if (l == 0)
            k_matmul_mfma<false><<<mmBlocks, 256, 0, stream>>>(
                in, L[l].W, dinv, stats, nullptr, nullptr, inv_n, bufA, n);
        else
            k_matmul_mfma<true><<<mmBlocks, 256, 0, stream>>>(
                in, L[l].W, dinv, stats, L[l - 1].g, L[l - 1].be, inv_n, bufA, n);
        k_gather<<<gatherBlocks, 256, 0, stream>>>(bufA, csr_src, row_ptr, dinv,
                                                   L[l].b, bufB, n);
        hipMemsetAsync(stats, 0, 2 * DIM * sizeof(float), stream);
        if (l < 2) {
            k_stats2<false><<<statBlocks, 256, 0, stream>>>(bufB, batch, stats,
                                                            nullptr, n);
        } else {
            hipMemsetAsync(gsum, 0, (size_t)G * DIM * sizeof(float), stream);
            k_stats2<true><<<statBlocks, 256, 0, stream>>>(bufB, batch, stats,
                                                           gsum, n);
        }
        in = bufB;
    }

    // pool finalize: mean -> BN affine
    k_pool_fin<<<G, 128, 0, stream>>>(gsum, batch, stats, g2, be2, out, n, inv_n);
}

// Round 9
// 332.581 us; speedup vs baseline: 6.0747x; 1.0398x over previous
//
#include <hip/hip_runtime.h>

#define DIM 128
constexpr float EPS = 1e-5f;

typedef _Float16 f16;
typedef __attribute__((ext_vector_type(8))) _Float16 f16x8;
typedef __attribute__((ext_vector_type(2))) _Float16 f16x2;
typedef __attribute__((ext_vector_type(4))) float f32x4;

// ---------------- degree (int) ----------------
__global__ void k_count_deg(const int* __restrict__ dst, int* __restrict__ degi, int E) {
    int e = blockIdx.x * blockDim.x + threadIdx.x;
    if (e < E) atomicAdd(&degi[dst[e]], 1);
}

// ---------------- scan pass 1: block-local exclusive scan + fused dinv ----------------
__global__ __launch_bounds__(256) void k_scan_local(const int* __restrict__ degi,
                                                    int* __restrict__ row_ptr,
                                                    float* __restrict__ dinv,
                                                    int* __restrict__ bsum, int n) {
    __shared__ int ws[4];
    int t = threadIdx.x, lane = t & 63, wv = t >> 6;
    int i0 = blockIdx.x * 1024 + t * 4;
    int v[4];
#pragma unroll
    for (int j = 0; j < 4; ++j) {
        int i = i0 + j;
        v[j] = (i < n) ? degi[i] : 0;
        if (i < n) dinv[i] = rsqrtf((float)v[j] + 1.0f);
    }
    int tsum = v[0] + v[1] + v[2] + v[3];
    int sc = tsum;
#pragma unroll
    for (int off = 1; off < 64; off <<= 1) {
        int u = __shfl_up(sc, off, 64);
        if (lane >= off) sc += u;
    }
    if (lane == 63) ws[wv] = sc;
    __syncthreads();
    int woff = 0;
    for (int j = 0; j < wv; ++j) woff += ws[j];
    int run = woff + sc - tsum;
#pragma unroll
    for (int j = 0; j < 4; ++j) {
        int i = i0 + j;
        if (i < n) row_ptr[i] = run;
        run += v[j];
    }
    if (t == 255) bsum[blockIdx.x] = woff + sc;
}

// ---------------- scan pass 2: add block offsets (inline bsum scan), cursor init ------
// assumes nb <= 64 (n <= 65536)
__global__ __launch_bounds__(256) void k_scan_add(int* __restrict__ row_ptr,
                                                  int* __restrict__ cursor,
                                                  const int* __restrict__ bsum,
                                                  int n, int E, int nb) {
    __shared__ int soff;
    int t = threadIdx.x;
    int seg = blockIdx.x >> 2;  // which 1024-segment this 256-block belongs to
    if (t < 64) {
        int v = (t < nb) ? bsum[t] : 0;
        int sc = v;
#pragma unroll
        for (int off = 1; off < 64; off <<= 1) {
            int u = __shfl_up(sc, off, 64);
            if (t >= off) sc += u;
        }
        if (t == seg) soff = sc - v;  // exclusive prefix for this segment
    }
    __syncthreads();
    int i = blockIdx.x * 256 + t;
    if (i < n) {
        int v = row_ptr[i] + soff;
        row_ptr[i] = v;
        cursor[i] = v;
    }
    if (i == 0) row_ptr[n] = E;
}

// ---------------- fill CSR: csr_src grouped by dst ----------------
__global__ void k_fill(const int* __restrict__ src, const int* __restrict__ dst,
                       int* __restrict__ cursor, int* __restrict__ csr_src, int E) {
    int e = blockIdx.x * blockDim.x + threadIdx.x;
    if (e >= E) return;
    int d = dst[e];
    int slot = atomicAdd(&cursor[d], 1);
    csr_src[slot] = src[e];
}

// ---------------- W split: f32 -> fp16 hi + fp16 lo*2048, transposed [col][k] --------
__global__ __launch_bounds__(256) void k_wsplit(const float* __restrict__ W0,
                                                const float* __restrict__ W1,
                                                const float* __restrict__ W2,
                                                f16* __restrict__ wt) {
    int layer = blockIdx.x >> 2;
    int quarter = blockIdx.x & 3;
    const float* W = layer == 0 ? W0 : (layer == 1 ? W1 : W2);
    f16* hi = wt + (size_t)layer * 2 * DIM * DIM;
    f16* lo = hi + DIM * DIM;
    for (int idx = quarter * 4096 + threadIdx.x; idx < (quarter + 1) * 4096; idx += 256) {
        int k = idx >> 7, c = idx & 127;
        float w = W[idx];
        f16 h = (f16)w;
        f16 l = (f16)((w - (float)h) * 2048.0f);
        hi[c * DIM + k] = h;
        lo[c * DIM + k] = l;
    }
}

// ---------------- MFMA GEMM: fp16 A, fp16 hi/lo W (2 products) ----------------
// out[row,:] = [relu(bn(in[row,:]))] @ W * dinv[row], stored fp16
template <bool PRE_BN>
__global__ __launch_bounds__(256) void k_matmul_mfma(
    const float* __restrict__ inF, const f16* __restrict__ inH,
    const f16* __restrict__ wt, const float* __restrict__ dinv,
    const float* __restrict__ stats, const float* __restrict__ g,
    const float* __restrict__ be, float inv_n, f16* __restrict__ out, int n) {
    __shared__ __align__(16) char sA[64 * 256];  // 64 rows x 128 fp16, swizzled
    __shared__ float sScale[DIM], sShift[DIM];

    int t = threadIdx.x;
    int w = t >> 6, l = t & 63;
    int row0 = blockIdx.x * 64;

    if (PRE_BN) {
        if (t < DIM) {
            float mu = stats[t] * inv_n;
            float var = stats[DIM + t] * inv_n - mu * mu;
            float sc = rsqrtf(var + EPS) * g[t];
            sScale[t] = sc;
            sShift[t] = be[t] - mu * sc;
        }
        __syncthreads();
    }

    // ---- W fragments (vectorized 16B loads from transposed split) ----
    f16x8 bh[2][4], bl[2][4];
    {
        int col = w * 32 + (l & 15);
        int ksub = (l >> 4) * 8;
        const f16* hi = wt;
        const f16* lo = wt + DIM * DIM;
#pragma unroll
        for (int ct = 0; ct < 2; ++ct) {
            int c2 = col + ct * 16;
#pragma unroll
            for (int kt = 0; kt < 4; ++kt) {
                bh[ct][kt] = *(const f16x8*)&hi[(size_t)c2 * DIM + kt * 32 + ksub];
                bl[ct][kt] = *(const f16x8*)&lo[(size_t)c2 * DIM + kt * 32 + ksub];
            }
        }
    }

    // ---- stage A tile (64x128 fp16), XOR-swizzled ----
    {
        int r = t >> 2;
        int row_g = row0 + r;
        if (row_g >= n) row_g = n - 1;
        int cbase = (t & 3) * 32;
#pragma unroll
        for (int o = 0; o < 4; ++o) {
            int c0 = cbase + o * 8;
            f16x8 h8;
            if (PRE_BN) {
                f16x8 v8 = *(const f16x8*)(inH + (size_t)row_g * DIM + c0);
#pragma unroll
                for (int j = 0; j < 8; ++j) {
                    float v = (float)v8[j] * sScale[c0 + j] + sShift[c0 + j];
                    h8[j] = (f16)fmaxf(v, 0.f);
                }
            } else {
                float4 v0 = *(const float4*)(inF + (size_t)row_g * DIM + c0);
                float4 v1 = *(const float4*)(inF + (size_t)row_g * DIM + c0 + 4);
                h8[0] = (f16)v0.x; h8[1] = (f16)v0.y; h8[2] = (f16)v0.z; h8[3] = (f16)v0.w;
                h8[4] = (f16)v1.x; h8[5] = (f16)v1.y; h8[6] = (f16)v1.z; h8[7] = (f16)v1.w;
            }
            int byte = (r * 256 + c0 * 2) ^ ((r & 7) << 4);
            *(f16x8*)(sA + byte) = h8;
        }
    }
    __syncthreads();

    // ---- MFMA main: 2 products (W-hi, W-lo) into separate accumulators ----
    f32x4 accA[4][2], accB[4][2];
#pragma unroll
    for (int rt = 0; rt < 4; ++rt)
#pragma unroll
        for (int ct = 0; ct < 2; ++ct) {
            accA[rt][ct] = (f32x4){0.f, 0.f, 0.f, 0.f};
            accB[rt][ct] = (f32x4){0.f, 0.f, 0.f, 0.f};
        }

#pragma unroll
    for (int rt = 0; rt < 4; ++rt) {
        int row_l = rt * 16 + (l & 15);
        int kb = (l >> 4) * 16;
        f16x8 a[4];
#pragma unroll
        for (int kt = 0; kt < 4; ++kt) {
            int byte = (row_l * 256 + kt * 64 + kb) ^ ((row_l & 7) << 4);
            a[kt] = *(const f16x8*)(sA + byte);
        }
#pragma unroll
        for (int ct = 0; ct < 2; ++ct) {
            f32x4 cA = accA[rt][ct], cB = accB[rt][ct];
#pragma unroll
            for (int kt = 0; kt < 4; ++kt) {
                cA = __builtin_amdgcn_mfma_f32_16x16x32_f16(a[kt], bh[ct][kt], cA, 0, 0, 0);
                cB = __builtin_amdgcn_mfma_f32_16x16x32_f16(a[kt], bl[ct][kt], cB, 0, 0, 0);
            }
            accA[rt][ct] = cA;
            accB[rt][ct] = cB;
        }
    }

    // ---- epilogue: combine, scale by dinv[row], store fp16 ----
    int colw = w * 32 + (l & 15);
#pragma unroll
    for (int rt = 0; rt < 4; ++rt) {
        int row_l = rt * 16 + ((l >> 4) << 2);
#pragma unroll
        for (int reg = 0; reg < 4; ++reg) {
            int gr = row0 + row_l + reg;
            if (gr >= n) continue;
            float dv = dinv[gr];
#pragma unroll
            for (int ct = 0; ct < 2; ++ct) {
                float v = (accA[rt][ct][reg] + accB[rt][ct][reg] * (1.0f / 2048.0f)) * dv;
                out[(size_t)gr * DIM + colw + ct * 16] = (f16)v;
            }
        }
    }
}

// ---------------- gather (fp16 in/out): agg[d] = dinv[d]*(sum_e hs[src]+hs[d]) + b ----
__global__ __launch_bounds__(256) void k_gather(const f16* __restrict__ hs,
                                                const int* __restrict__ csr_src,
                                                const int* __restrict__ row_ptr,
                                                const float* __restrict__ dinv,
                                                const float* __restrict__ b,
                                                f16* __restrict__ agg, int n) {
    int node = (blockIdx.x * 256 + threadIdx.x) >> 6;
    if (node >= n) return;
    int l = threadIdx.x & 63;
    int grp = l >> 4;      // 0..3: edge-parallel group
    int c8 = (l & 15) * 8; // 8 channels per lane (16 B fp16)

    float acc[8] = {};
    int beg = row_ptr[node], end = row_ptr[node + 1];

    int e = beg + grp;
    for (; e + 4 < end; e += 8) {
        int s0 = csr_src[e];
        int s1 = csr_src[e + 4];
        f16x8 a = *(const f16x8*)(hs + (size_t)s0 * DIM + c8);
        f16x8 c = *(const f16x8*)(hs + (size_t)s1 * DIM + c8);
#pragma unroll
        for (int j = 0; j < 8; ++j) acc[j] += (float)a[j] + (float)c[j];
    }
    for (; e < end; e += 4) {
        int s0 = csr_src[e];
        f16x8 a = *(const f16x8*)(hs + (size_t)s0 * DIM + c8);
#pragma unroll
        for (int j = 0; j < 8; ++j) acc[j] += (float)a[j];
    }

#pragma unroll
    for (int j = 0; j < 8; ++j) {
        acc[j] += __shfl_xor(acc[j], 16, 64);
        acc[j] += __shfl_xor(acc[j], 32, 64);
    }

    if (grp == 0) {
        f16x8 hv = *(const f16x8*)(hs + (size_t)node * DIM + c8);
        float dv = dinv[node];
        f32x4 bb0 = *(const f32x4*)(b + c8);
        f32x4 bb1 = *(const f32x4*)(b + c8 + 4);
        f16x8 ov;
#pragma unroll
        for (int j = 0; j < 4; ++j) {
            ov[j] = (f16)((acc[j] + (float)hv[j]) * dv + bb0[j]);
            ov[j + 4] = (f16)((acc[j + 4] + (float)hv[j + 4]) * dv + bb1[j]);
        }
        *(f16x8*)(agg + (size_t)node * DIM + c8) = ov;
    }
}

// ---------------- BN stats over fp16 x (+optional fused pool-sum) ----------------
template <bool POOL>
__global__ __launch_bounds__(256) void k_stats2(const f16* __restrict__ x,
                                                const int* __restrict__ batch,
                                                float* __restrict__ stats,
                                                float* __restrict__ gsum, int n) {
    int t = threadIdx.x;
    int c2 = (t & 63) * 2;
    int rq = t >> 6;  // 0..3
    int r0 = blockIdx.x * 128;
    int r1 = min(n, r0 + 128);

    float2 s = {0.f, 0.f}, s2 = {0.f, 0.f}, ps = {0.f, 0.f};
    int curseg = -1;
    int b0 = POOL ? batch[0] : 0;

    for (int r = r0 + rq; r < r1; r += 4) {
        f16x2 h2 = *(const f16x2*)&x[(size_t)r * DIM + c2];
        float vx = (float)h2[0], vy = (float)h2[1];
        s.x += vx; s.y += vy;
        s2.x += vx * vx; s2.y += vy * vy;
        if (POOL) {
            int seg = batch[r] - b0;
            if (seg != curseg) {
                if (curseg >= 0) {
                    atomicAdd(&gsum[(size_t)curseg * DIM + c2], ps.x);
                    atomicAdd(&gsum[(size_t)curseg * DIM + c2 + 1], ps.y);
                }
                ps.x = 0.f; ps.y = 0.f;
                curseg = seg;
            }
            ps.x += vx; ps.y += vy;
        }
    }
    if (POOL && curseg >= 0) {
        atomicAdd(&gsum[(size_t)curseg * DIM + c2], ps.x);
        atomicAdd(&gsum[(size_t)curseg * DIM + c2 + 1], ps.y);
    }

    __shared__ float2 ls[256], lq[256];
    ls[t] = s; lq[t] = s2;
    __syncthreads();
    if (t < 64) {
#pragma unroll
        for (int j = 1; j < 4; ++j) {
            s.x += ls[t + 64 * j].x; s.y += ls[t + 64 * j].y;
            s2.x += lq[t + 64 * j].x; s2.y += lq[t + 64 * j].y;
        }
        atomicAdd(&stats[c2], s.x);
        atomicAdd(&stats[c2 + 1], s.y);
        atomicAdd(&stats[DIM + c2], s2.x);
        atomicAdd(&stats[DIM + c2 + 1], s2.y);
    }
}

// ---------------- pool finalize: out = mean*scale + shift ----------------
__global__ __launch_bounds__(128) void k_pool_fin(const float* __restrict__ gsum,
                                                  const int* __restrict__ batch,
                                                  const float* __restrict__ stats,
                                                  const float* __restrict__ g,
                                                  const float* __restrict__ be,
                                                  float* __restrict__ out,
                                                  int n, float inv_n) {
    int gseg = blockIdx.x;
    int c = threadIdx.x;
    int b0 = batch[0];
    int target = b0 + gseg;
    int lo = 0, hi = n;
    while (lo < hi) { int mid = (lo + hi) >> 1; if (batch[mid] < target) lo = mid + 1; else hi = mid; }
    int start = lo;
    lo = start; hi = n;
    while (lo < hi) { int mid = (lo + hi) >> 1; if (batch[mid] < target + 1) lo = mid + 1; else hi = mid; }
    int end = lo;
    int cnt = end - start;

    float mu = stats[c] * inv_n;
    float var = stats[DIM + c] * inv_n - mu * mu;
    float scale = rsqrtf(var + EPS) * g[c];
    float shift = be[c] - mu * scale;
    float o = 0.f;
    if (cnt > 0) o = (gsum[(size_t)gseg * DIM + c] / (float)cnt) * scale + shift;
    out[(size_t)gseg * DIM + c] = o;
}

// ---------------- launch ----------------
extern "C" void kernel_launch(void* const* d_in, const int* in_sizes, int n_in,
                              void* d_out, int out_size, void* d_ws, size_t ws_size,
                              hipStream_t stream) {
    const float* x = (const float*)d_in[0];
    const int* edge_index = (const int*)d_in[1];
    const int* batch = (const int*)d_in[3];
    const float* W1 = (const float*)d_in[4];
    const float* b1 = (const float*)d_in[5];
    const float* g1 = (const float*)d_in[6];
    const float* be1 = (const float*)d_in[7];
    const float* Wm = (const float*)d_in[8];
    const float* bm = (const float*)d_in[9];
    const float* gm = (const float*)d_in[10];
    const float* bem = (const float*)d_in[11];
    const float* W2 = (const float*)d_in[12];
    const float* b2 = (const float*)d_in[13];
    const float* g2 = (const float*)d_in[14];
    const float* be2 = (const float*)d_in[15];

    int n = in_sizes[0] / DIM;
    int E = in_sizes[1] / 2;
    int G = out_size / DIM;

    const int* srcI = edge_index;
    const int* dstI = edge_index + E;

    char* p = (char*)d_ws;
    f16* bufA = (f16*)p;                p += (size_t)n * DIM * 2;   // hs fp16
    f16* bufB = (f16*)p;                p += (size_t)n * DIM * 2;   // agg fp16
    float* dinv = (float*)p;            p += (size_t)n * 4;
    int* row_ptr = (int*)p;             p += (size_t)(n + 1) * 4;
    int* cursor = (int*)p;              p += (size_t)n * 4;
    int* csr_src = (int*)p;             p += (size_t)E * 4;
    int* bsum = (int*)p;                p += 64 * 4;
    // ---- contiguous zero region ----
    char* zero0 = p;
    int* degi = (int*)p;                p += (size_t)n * 4;
    float* stats3 = (float*)p;          p += 3 * 2 * DIM * 4;       // per-layer stats
    float* gsum = (float*)p;            p += (size_t)G * DIM * 4;
    size_t zero_bytes = (size_t)(p - zero0);
    // ---- W split buffer ----
    f16* wsplit = (f16*)p;              p += (size_t)3 * 2 * DIM * DIM * 2;

    float* out = (float*)d_out;
    float inv_n = 1.0f / (float)n;
    int nb = (n + 1023) / 1024;  // <= 64 assumed (n <= 65536)

    // ---- init + CSR build ----
    hipMemsetAsync(zero0, 0, zero_bytes, stream);
    k_count_deg<<<(E + 255) / 256, 256, 0, stream>>>(dstI, degi, E);
    k_scan_local<<<nb, 256, 0, stream>>>(degi, row_ptr, dinv, bsum, n);
    k_scan_add<<<(n + 255) / 256, 256, 0, stream>>>(row_ptr, cursor, bsum, n, E, nb);
    k_fill<<<(E + 255) / 256, 256, 0, stream>>>(srcI, dstI, cursor, csr_src, E);
    k_wsplit<<<12, 256, 0, stream>>>(W1, Wm, W2, wsplit);

    struct Layer { const float *b, *g, *be; };
    Layer L[3] = {{b1, g1, be1}, {bm, gm, bem}, {b2, g2, be2}};

    int mmBlocks = (n + 63) / 64;
    int gatherBlocks = (n + 3) / 4;
    int statBlocks = (n + 127) / 128;
    for (int l = 0; l < 3; ++l) {
        const f16* wl = wsplit + (size_t)l * 2 * DIM * DIM;
        float* stats_l = stats3 + l * 2 * DIM;
        if (l == 0)
            k_matmul_mfma<false><<<mmBlocks, 256, 0, stream>>>(
                x, nullptr, wl, dinv, nullptr, nullptr, nullptr, inv_n, bufA, n);
        else
            k_matmul_mfma<true><<<mmBlocks, 256, 0, stream>>>(
                nullptr, bufB, wl, dinv, stats3 + (l - 1) * 2 * DIM,
                L[l - 1].g, L[l - 1].be, inv_n, bufA, n);
        k_gather<<<gatherBlocks, 256, 0, stream>>>(bufA, csr_src, row_ptr, dinv,
                                                   L[l].b, bufB, n);
        if (l < 2)
            k_stats2<false><<<statBlocks, 256, 0, stream>>>(bufB, batch, stats_l,
                                                            nullptr, n);
        else
            k_stats2<true><<<statBlocks, 256, 0, stream>>>(bufB, batch, stats_l,
                                                           gsum, n);
    }

    // pool finalize: mean -> final BN affine
    k_pool_fin<<<G, 128, 0, stream>>>(gsum, batch, stats3 + 2 * 2 * DIM, g2, be2,
                                      out, n, inv_n);
}

// Round 10
// 280.801 us; speedup vs baseline: 7.1949x; 1.1844x over previous
//
#include <hip/hip_runtime.h>

#define DIM 128
constexpr float EPS = 1e-5f;
#define SHARD 2048  // 8 shards x 256 floats (sum[128] + sumsq[128]) per layer

typedef _Float16 f16;
typedef __attribute__((ext_vector_type(8))) _Float16 f16x8;
typedef __attribute__((ext_vector_type(4))) float f32x4;

// ---------------- prep: W split (blocks 0..11) + degree count (blocks 12..) ----------
__global__ __launch_bounds__(256) void k_prep(const int* __restrict__ dst,
                                              int* __restrict__ degi, int E,
                                              const float* __restrict__ W0,
                                              const float* __restrict__ W1,
                                              const float* __restrict__ W2,
                                              f16* __restrict__ wt) {
    if (blockIdx.x < 12) {
        int layer = blockIdx.x >> 2;
        int quarter = blockIdx.x & 3;
        const float* W = layer == 0 ? W0 : (layer == 1 ? W1 : W2);
        f16* hi = wt + (size_t)layer * 2 * DIM * DIM;
        f16* lo = hi + DIM * DIM;
        for (int idx = quarter * 4096 + threadIdx.x; idx < (quarter + 1) * 4096;
             idx += 256) {
            int k = idx >> 7, c = idx & 127;
            float w = W[idx];
            f16 h = (f16)w;
            f16 l = (f16)((w - (float)h) * 2048.0f);
            hi[c * DIM + k] = h;
            lo[c * DIM + k] = l;
        }
    } else {
        int e = (blockIdx.x - 12) * 256 + threadIdx.x;
        if (e < E) atomicAdd(&degi[dst[e]], 1);
    }
}

// ---------------- scan pass 1: block-local exclusive scan + fused dinv ----------------
__global__ __launch_bounds__(256) void k_scan_local(const int* __restrict__ degi,
                                                    int* __restrict__ row_ptr,
                                                    float* __restrict__ dinv,
                                                    int* __restrict__ bsum, int n) {
    __shared__ int ws[4];
    int t = threadIdx.x, lane = t & 63, wv = t >> 6;
    int i0 = blockIdx.x * 1024 + t * 4;
    int v[4];
#pragma unroll
    for (int j = 0; j < 4; ++j) {
        int i = i0 + j;
        v[j] = (i < n) ? degi[i] : 0;
        if (i < n) dinv[i] = rsqrtf((float)v[j] + 1.0f);
    }
    int tsum = v[0] + v[1] + v[2] + v[3];
    int sc = tsum;
#pragma unroll
    for (int off = 1; off < 64; off <<= 1) {
        int u = __shfl_up(sc, off, 64);
        if (lane >= off) sc += u;
    }
    if (lane == 63) ws[wv] = sc;
    __syncthreads();
    int woff = 0;
    for (int j = 0; j < wv; ++j) woff += ws[j];
    int run = woff + sc - tsum;
#pragma unroll
    for (int j = 0; j < 4; ++j) {
        int i = i0 + j;
        if (i < n) row_ptr[i] = run;
        run += v[j];
    }
    if (t == 255) bsum[blockIdx.x] = woff + sc;
}

// ---------------- scan pass 2: add block offsets (inline bsum scan), cursor init ------
__global__ __launch_bounds__(256) void k_scan_add(int* __restrict__ row_ptr,
                                                  int* __restrict__ cursor,
                                                  const int* __restrict__ bsum,
                                                  int n, int E, int nb) {
    __shared__ int soff;
    int t = threadIdx.x;
    int seg = blockIdx.x >> 2;
    if (t < 64) {
        int v = (t < nb) ? bsum[t] : 0;
        int sc = v;
#pragma unroll
        for (int off = 1; off < 64; off <<= 1) {
            int u = __shfl_up(sc, off, 64);
            if (t >= off) sc += u;
        }
        if (t == seg) soff = sc - v;
    }
    __syncthreads();
    int i = blockIdx.x * 256 + t;
    if (i < n) {
        int v = row_ptr[i] + soff;
        row_ptr[i] = v;
        cursor[i] = v;
    }
    if (i == 0) row_ptr[n] = E;
}

// ---------------- fill CSR: csr_src grouped by dst ----------------
__global__ void k_fill(const int* __restrict__ src, const int* __restrict__ dst,
                       int* __restrict__ cursor, int* __restrict__ csr_src, int E) {
    int e = blockIdx.x * blockDim.x + threadIdx.x;
    if (e >= E) return;
    int d = dst[e];
    int slot = atomicAdd(&cursor[d], 1);
    csr_src[slot] = src[e];
}

// ---------------- MFMA GEMM: fp16 A, fp16 hi/lo W (2 products) ----------------
// stats arg = 8-sharded per-layer stats_part (summed in prologue)
template <bool PRE_BN>
__global__ __launch_bounds__(256) void k_matmul_mfma(
    const float* __restrict__ inF, const f16* __restrict__ inH,
    const f16* __restrict__ wt, const float* __restrict__ dinv,
    const float* __restrict__ stats, const float* __restrict__ g,
    const float* __restrict__ be, float inv_n, f16* __restrict__ out, int n) {
    __shared__ __align__(16) char sA[64 * 256];
    __shared__ float sScale[DIM], sShift[DIM];

    int t = threadIdx.x;
    int w = t >> 6, l = t & 63;
    int row0 = blockIdx.x * 64;

    if (PRE_BN) {
        if (t < DIM) {
            float su = 0.f, sq = 0.f;
#pragma unroll
            for (int s = 0; s < 8; ++s) {
                su += stats[s * 256 + t];
                sq += stats[s * 256 + 128 + t];
            }
            float mu = su * inv_n;
            float var = sq * inv_n - mu * mu;
            float sc = rsqrtf(var + EPS) * g[t];
            sScale[t] = sc;
            sShift[t] = be[t] - mu * sc;
        }
        __syncthreads();
    }

    // ---- W fragments (16B loads from transposed split) ----
    f16x8 bh[2][4], bl[2][4];
    {
        int col = w * 32 + (l & 15);
        int ksub = (l >> 4) * 8;
        const f16* hi = wt;
        const f16* lo = wt + DIM * DIM;
#pragma unroll
        for (int ct = 0; ct < 2; ++ct) {
            int c2 = col + ct * 16;
#pragma unroll
            for (int kt = 0; kt < 4; ++kt) {
                bh[ct][kt] = *(const f16x8*)&hi[(size_t)c2 * DIM + kt * 32 + ksub];
                bl[ct][kt] = *(const f16x8*)&lo[(size_t)c2 * DIM + kt * 32 + ksub];
            }
        }
    }

    // ---- stage A tile (64x128 fp16), XOR-swizzled ----
    {
        int r = t >> 2;
        int row_g = row0 + r;
        if (row_g >= n) row_g = n - 1;
        int cbase = (t & 3) * 32;
#pragma unroll
        for (int o = 0; o < 4; ++o) {
            int c0 = cbase + o * 8;
            f16x8 h8;
            if (PRE_BN) {
                f16x8 v8 = *(const f16x8*)(inH + (size_t)row_g * DIM + c0);
#pragma unroll
                for (int j = 0; j < 8; ++j) {
                    float v = (float)v8[j] * sScale[c0 + j] + sShift[c0 + j];
                    h8[j] = (f16)fmaxf(v, 0.f);
                }
            } else {
                float4 v0 = *(const float4*)(inF + (size_t)row_g * DIM + c0);
                float4 v1 = *(const float4*)(inF + (size_t)row_g * DIM + c0 + 4);
                h8[0] = (f16)v0.x; h8[1] = (f16)v0.y; h8[2] = (f16)v0.z; h8[3] = (f16)v0.w;
                h8[4] = (f16)v1.x; h8[5] = (f16)v1.y; h8[6] = (f16)v1.z; h8[7] = (f16)v1.w;
            }
            int byte = (r * 256 + c0 * 2) ^ ((r & 7) << 4);
            *(f16x8*)(sA + byte) = h8;
        }
    }
    __syncthreads();

    // ---- MFMA main: 2 products (W-hi, W-lo) ----
    f32x4 accA[4][2], accB[4][2];
#pragma unroll
    for (int rt = 0; rt < 4; ++rt)
#pragma unroll
        for (int ct = 0; ct < 2; ++ct) {
            accA[rt][ct] = (f32x4){0.f, 0.f, 0.f, 0.f};
            accB[rt][ct] = (f32x4){0.f, 0.f, 0.f, 0.f};
        }

#pragma unroll
    for (int rt = 0; rt < 4; ++rt) {
        int row_l = rt * 16 + (l & 15);
        int kb = (l >> 4) * 16;
        f16x8 a[4];
#pragma unroll
        for (int kt = 0; kt < 4; ++kt) {
            int byte = (row_l * 256 + kt * 64 + kb) ^ ((row_l & 7) << 4);
            a[kt] = *(const f16x8*)(sA + byte);
        }
#pragma unroll
        for (int ct = 0; ct < 2; ++ct) {
            f32x4 cA = accA[rt][ct], cB = accB[rt][ct];
#pragma unroll
            for (int kt = 0; kt < 4; ++kt) {
                cA = __builtin_amdgcn_mfma_f32_16x16x32_f16(a[kt], bh[ct][kt], cA, 0, 0, 0);
                cB = __builtin_amdgcn_mfma_f32_16x16x32_f16(a[kt], bl[ct][kt], cB, 0, 0, 0);
            }
            accA[rt][ct] = cA;
            accB[rt][ct] = cB;
        }
    }

    // ---- epilogue: combine, scale by dinv[row], store fp16 ----
    int colw = w * 32 + (l & 15);
#pragma unroll
    for (int rt = 0; rt < 4; ++rt) {
        int row_l = rt * 16 + ((l >> 4) << 2);
#pragma unroll
        for (int reg = 0; reg < 4; ++reg) {
            int gr = row0 + row_l + reg;
            if (gr >= n) continue;
            float dv = dinv[gr];
#pragma unroll
            for (int ct = 0; ct < 2; ++ct) {
                float v = (accA[rt][ct][reg] + accB[rt][ct][reg] * (1.0f / 2048.0f)) * dv;
                out[(size_t)gr * DIM + colw + ct * 16] = (f16)v;
            }
        }
    }
}

// ---------------- fused gather + BN stats (+ pool): 16 waves = 16 nodes/block --------
// agg[d] = dinv[d]*(sum_e hs[src]+hs[d]) + b; stats_part[8][256] sharded atomics;
// POOL: segmented per-graph sums of f32 agg rows -> gsum (batch sorted).
template <bool POOL>
__global__ __launch_bounds__(1024) void k_gs(const f16* __restrict__ hs,
                                             const int* __restrict__ csr_src,
                                             const int* __restrict__ row_ptr,
                                             const float* __restrict__ dinv,
                                             const float* __restrict__ b,
                                             const int* __restrict__ batch,
                                             f16* __restrict__ agg,
                                             float* __restrict__ stats_part,
                                             float* __restrict__ gsum, int n) {
    __shared__ float sSum[16][DIM];
    __shared__ float sSq[16][DIM];
    __shared__ int sSeg[16];

    int t = threadIdx.x;
    int wv = t >> 6, l = t & 63;
    int node = blockIdx.x * 16 + wv;
    int grp = l >> 4;
    int c8 = (l & 15) * 8;
    bool valid = node < n;

    float acc[8] = {};
    int beg = 0, end = 0;
    if (valid) {
        beg = row_ptr[node];
        end = row_ptr[node + 1];
    }
    int e = beg + grp;
    for (; e + 4 < end; e += 8) {
        int s0 = csr_src[e];
        int s1 = csr_src[e + 4];
        f16x8 a = *(const f16x8*)(hs + (size_t)s0 * DIM + c8);
        f16x8 c = *(const f16x8*)(hs + (size_t)s1 * DIM + c8);
#pragma unroll
        for (int j = 0; j < 8; ++j) acc[j] += (float)a[j] + (float)c[j];
    }
    for (; e < end; e += 4) {
        int s0 = csr_src[e];
        f16x8 a = *(const f16x8*)(hs + (size_t)s0 * DIM + c8);
#pragma unroll
        for (int j = 0; j < 8; ++j) acc[j] += (float)a[j];
    }
#pragma unroll
    for (int j = 0; j < 8; ++j) {
        acc[j] += __shfl_xor(acc[j], 16, 64);
        acc[j] += __shfl_xor(acc[j], 32, 64);
    }

    if (grp == 0) {
        if (valid) {
            f16x8 hv = *(const f16x8*)(hs + (size_t)node * DIM + c8);
            float dv = dinv[node];
            f32x4 bb0 = *(const f32x4*)(b + c8);
            f32x4 bb1 = *(const f32x4*)(b + c8 + 4);
            float o[8];
#pragma unroll
            for (int j = 0; j < 4; ++j) {
                o[j] = (acc[j] + (float)hv[j]) * dv + bb0[j];
                o[j + 4] = (acc[j + 4] + (float)hv[j + 4]) * dv + bb1[j];
            }
            f16x8 ov;
#pragma unroll
            for (int j = 0; j < 8; ++j) ov[j] = (f16)o[j];
            *(f16x8*)(agg + (size_t)node * DIM + c8) = ov;
            f32x4 s0 = {o[0], o[1], o[2], o[3]}, s1 = {o[4], o[5], o[6], o[7]};
            f32x4 q0 = {o[0]*o[0], o[1]*o[1], o[2]*o[2], o[3]*o[3]};
            f32x4 q1 = {o[4]*o[4], o[5]*o[5], o[6]*o[6], o[7]*o[7]};
            *(f32x4*)&sSum[wv][c8] = s0;
            *(f32x4*)&sSum[wv][c8 + 4] = s1;
            *(f32x4*)&sSq[wv][c8] = q0;
            *(f32x4*)&sSq[wv][c8 + 4] = q1;
            if (POOL && l == 0) sSeg[wv] = batch[node] - batch[0];
        } else {
            f32x4 z = {0.f, 0.f, 0.f, 0.f};
            *(f32x4*)&sSum[wv][c8] = z;
            *(f32x4*)&sSum[wv][c8 + 4] = z;
            *(f32x4*)&sSq[wv][c8] = z;
            *(f32x4*)&sSq[wv][c8 + 4] = z;
        }
    }
    __syncthreads();

    int shard = (blockIdx.x & 7) * 256;
    if (t < 128) {
        float s = 0.f;
#pragma unroll
        for (int w = 0; w < 16; ++w) s += sSum[w][t];
        atomicAdd(&stats_part[shard + t], s);
    } else if (t < 256) {
        int ch = t - 128;
        float s = 0.f;
#pragma unroll
        for (int w = 0; w < 16; ++w) s += sSq[w][ch];
        atomicAdd(&stats_part[shard + 128 + ch], s);
    }

    if (POOL && t < 128) {
        int cur = -1;
        float a = 0.f;
        for (int w = 0; w < 16; ++w) {
            if (blockIdx.x * 16 + w >= n) break;
            int seg = sSeg[w];
            if (seg != cur) {
                if (cur >= 0) atomicAdd(&gsum[(size_t)cur * DIM + t], a);
                a = 0.f;
                cur = seg;
            }
            a += sSum[w][t];
        }
        if (cur >= 0) atomicAdd(&gsum[(size_t)cur * DIM + t], a);
    }
}

// ---------------- pool finalize: out = mean*scale + shift ----------------
__global__ __launch_bounds__(128) void k_pool_fin(const float* __restrict__ gsum,
                                                  const int* __restrict__ batch,
                                                  const float* __restrict__ stats,
                                                  const float* __restrict__ g,
                                                  const float* __restrict__ be,
                                                  float* __restrict__ out,
                                                  int n, float inv_n) {
    int gseg = blockIdx.x;
    int c = threadIdx.x;
    int b0 = batch[0];
    int target = b0 + gseg;
    int lo = 0, hi = n;
    while (lo < hi) { int mid = (lo + hi) >> 1; if (batch[mid] < target) lo = mid + 1; else hi = mid; }
    int start = lo;
    lo = start; hi = n;
    while (lo < hi) { int mid = (lo + hi) >> 1; if (batch[mid] < target + 1) lo = mid + 1; else hi = mid; }
    int end = lo;
    int cnt = end - start;

    float su = 0.f, sq = 0.f;
#pragma unroll
    for (int s = 0; s < 8; ++s) {
        su += stats[s * 256 + c];
        sq += stats[s * 256 + 128 + c];
    }
    float mu = su * inv_n;
    float var = sq * inv_n - mu * mu;
    float scale = rsqrtf(var + EPS) * g[c];
    float shift = be[c] - mu * scale;
    float o = 0.f;
    if (cnt > 0) o = (gsum[(size_t)gseg * DIM + c] / (float)cnt) * scale + shift;
    out[(size_t)gseg * DIM + c] = o;
}

// ---------------- launch ----------------
extern "C" void kernel_launch(void* const* d_in, const int* in_sizes, int n_in,
                              void* d_out, int out_size, void* d_ws, size_t ws_size,
                              hipStream_t stream) {
    const float* x = (const float*)d_in[0];
    const int* edge_index = (const int*)d_in[1];
    const int* batch = (const int*)d_in[3];
    const float* W1 = (const float*)d_in[4];
    const float* b1 = (const float*)d_in[5];
    const float* g1 = (const float*)d_in[6];
    const float* be1 = (const float*)d_in[7];
    const float* Wm = (const float*)d_in[8];
    const float* bm = (const float*)d_in[9];
    const float* gm = (const float*)d_in[10];
    const float* bem = (const float*)d_in[11];
    const float* W2 = (const float*)d_in[12];
    const float* b2 = (const float*)d_in[13];
    const float* g2 = (const float*)d_in[14];
    const float* be2 = (const float*)d_in[15];

    int n = in_sizes[0] / DIM;
    int E = in_sizes[1] / 2;
    int G = out_size / DIM;

    const int* srcI = edge_index;
    const int* dstI = edge_index + E;

    char* p = (char*)d_ws;
    f16* bufA = (f16*)p;                p += (size_t)n * DIM * 2;   // hs fp16
    f16* bufB = (f16*)p;                p += (size_t)n * DIM * 2;   // agg fp16
    float* dinv = (float*)p;            p += (size_t)n * 4;
    int* row_ptr = (int*)p;             p += (size_t)(n + 1) * 4;
    int* cursor = (int*)p;              p += (size_t)n * 4;
    int* csr_src = (int*)p;             p += (size_t)E * 4;
    int* bsum = (int*)p;                p += 64 * 4;
    // ---- contiguous zero region ----
    char* zero0 = p;
    int* degi = (int*)p;                p += (size_t)n * 4;
    float* stats3 = (float*)p;          p += 3 * SHARD * 4;         // 8-sharded per layer
    float* gsum = (float*)p;            p += (size_t)G * DIM * 4;
    size_t zero_bytes = (size_t)(p - zero0);
    // ---- W split buffer ----
    f16* wsplit = (f16*)p;              p += (size_t)3 * 2 * DIM * DIM * 2;

    float* out = (float*)d_out;
    float inv_n = 1.0f / (float)n;
    int nb = (n + 1023) / 1024;  // <= 64 assumed

    // ---- init + CSR build + W split ----
    hipMemsetAsync(zero0, 0, zero_bytes, stream);
    k_prep<<<12 + (E + 255) / 256, 256, 0, stream>>>(dstI, degi, E, W1, Wm, W2, wsplit);
    k_scan_local<<<nb, 256, 0, stream>>>(degi, row_ptr, dinv, bsum, n);
    k_scan_add<<<(n + 255) / 256, 256, 0, stream>>>(row_ptr, cursor, bsum, n, E, nb);
    k_fill<<<(E + 255) / 256, 256, 0, stream>>>(srcI, dstI, cursor, csr_src, E);

    struct Layer { const float *b, *g, *be; };
    Layer L[3] = {{b1, g1, be1}, {bm, gm, bem}, {b2, g2, be2}};

    int mmBlocks = (n + 63) / 64;
    int gsBlocks = (n + 15) / 16;
    for (int l = 0; l < 3; ++l) {
        const f16* wl = wsplit + (size_t)l * 2 * DIM * DIM;
        float* stats_l = stats3 + l * SHARD;
        if (l == 0)
            k_matmul_mfma<false><<<mmBlocks, 256, 0, stream>>>(
                x, nullptr, wl, dinv, nullptr, nullptr, nullptr, inv_n, bufA, n);
        else
            k_matmul_mfma<true><<<mmBlocks, 256, 0, stream>>>(
                nullptr, bufB, wl, dinv, stats3 + (l - 1) * SHARD,
                L[l - 1].g, L[l - 1].be, inv_n, bufA, n);
        if (l < 2)
            k_gs<false><<<gsBlocks, 1024, 0, stream>>>(bufA, csr_src, row_ptr, dinv,
                                                       L[l].b, batch, bufB, stats_l,
                                                       nullptr, n);
        else
            k_gs<true><<<gsBlocks, 1024, 0, stream>>>(bufA, csr_src, row_ptr, dinv,
                                                      L[l].b, batch, bufB, stats_l,
                                                      gsum, n);
    }

    // pool finalize: mean -> final BN affine
    k_pool_fin<<<G, 128, 0, stream>>>(gsum, batch, stats3 + 2 * SHARD, g2, be2,
                                      out, n, inv_n);
}